// Round 3
// baseline (240.483 us; speedup 1.0000x reference)
//
#include <hip/hip_runtime.h>

#define B_ 2
#define T_ 2048
#define H_ 12
#define E_ 64
#define M_ 256
#define BLK 64
#define NBLK 32

typedef _Float16 f16;
typedef f16 f16x2 __attribute__((ext_vector_type(2)));
typedef f16 f16x4 __attribute__((ext_vector_type(4)));
typedef f16 f16x8 __attribute__((ext_vector_type(8)));
typedef float f32x4 __attribute__((ext_vector_type(4)));

#define MFMA16(Av, Bv, Cv) __builtin_amdgcn_mfma_f32_16x16x32_f16(Av, Bv, Cv, 0, 0, 0)

constexpr float DN = 0.35355339059327373f;        // sqrt(temp)
constexpr float HALF_LOG_M = 2.7725887222397811f; // 0.5*ln(256)
constexpr float LN_CQ = 5.545177444479562f;       // ln(256): q' scale (denormal guard)
constexpr float LN_CK = 2.772588722239781f;       // ln(16):  k' scale

__device__ __forceinline__ unsigned fkey(float f) {
  unsigned u = __float_as_uint(f);
  return (u & 0x80000000u) ? ~u : (u | 0x80000000u);
}
__device__ __forceinline__ float unfkey(unsigned k) {
  return (k & 0x80000000u) ? __uint_as_float(k & 0x7fffffffu) : __uint_as_float(~k);
}

// ---------------- workspace layout (bytes) ----------------
// 0        : skb    uint[24]                  (pad 256)
// 256      : projh  f16 [256][64]    32768 -> 33024
// 33024    : k_prime f16 [24][2048][256] 25165824 -> 25198848
// 25198848 : kvacc4 f32 [4][24][80][256] 7864320 -> 33063168  (~33 MB)
#define PSTRIDE 491520  // 24*80*256

__global__ void init_ws(unsigned* __restrict__ skb, f16* __restrict__ projh,
                        const float* __restrict__ proj) {
  int i = blockIdx.x * blockDim.x + threadIdx.x;
  if (i < B_ * H_) skb[i] = 0u;
  if (i < M_ * E_) projh[i] = (f16)proj[i];
}

// MODE 0: global max of k_shift -> skb (atomicMax)
// MODE 1: k_prime = 16*exp(k_shift - s_k) -> f16 global
template <int MODE>
__global__ __launch_bounds__(512) void kshift_kernel(
    const float* __restrict__ key, const f16* __restrict__ projh,
    unsigned* __restrict__ skb, f16* __restrict__ k_prime) {
  __shared__ float red[8];
  const int blk = blockIdx.x;  // 24 bh x 8 chunks
  const int chunk = blk & 7, bh = blk >> 3;
  const int b = bh / H_, h = bh % H_;
  const int t = threadIdx.x;
  const int w = t >> 6, l = t & 63, l15 = l & 15, g4 = l >> 4;
  const int rblk = w & 3, cH = w >> 2, r0 = rblk * 16;
  const float skv = (MODE == 1) ? unfkey(skb[bh]) : 0.f;
  float lmax = -3.0e38f;

  for (int ti = 0; ti < 4; ++ti) {
    const int t0 = chunk * 256 + ti * 64;
    f16x8 avk[2];
    float kdl = 0.f;
    {
      const float* gk = key + (((size_t)b * T_ + t0 + r0 + l15) * H_ + h) * E_;
#pragma unroll
      for (int kk = 0; kk < 2; ++kk) {
        int e0 = kk * 32 + g4 * 8;
        float4 a = *(const float4*)(gk + e0);
        float4 bq = *(const float4*)(gk + e0 + 4);
        float x0 = a.x * DN, x1 = a.y * DN, x2 = a.z * DN, x3 = a.w * DN;
        float y0 = bq.x * DN, y1 = bq.y * DN, y2 = bq.z * DN, y3 = bq.w * DN;
        avk[kk] = (f16x8){(f16)x0, (f16)x1, (f16)x2, (f16)x3,
                          (f16)y0, (f16)y1, (f16)y2, (f16)y3};
        kdl += x0 * x0 + x1 * x1 + x2 * x2 + x3 * x3 + y0 * y0 + y1 * y1 + y2 * y2 + y3 * y3;
      }
      kdl *= 0.5f;
      kdl += __shfl_xor(kdl, 16);
      kdl += __shfl_xor(kdl, 32);
    }
    f32x4 acc[8];
#pragma unroll
    for (int ct = 0; ct < 8; ++ct) acc[ct] = (f32x4){0.f, 0.f, 0.f, 0.f};
#pragma unroll
    for (int kk = 0; kk < 2; ++kk)
#pragma unroll
      for (int ct = 0; ct < 8; ++ct) {
        int m = cH * 128 + ct * 16 + l15;
        f16x8 bv = *(const f16x8*)(projh + m * E_ + kk * 32 + g4 * 8);
        acc[ct] = MFMA16(avk[kk], bv, acc[ct]);
      }
    float kd4[4];
#pragma unroll
    for (int r = 0; r < 4; ++r) kd4[r] = __shfl(kdl, (l & 48) + g4 * 4 + r);
    if (MODE == 0) {
#pragma unroll
      for (int ct = 0; ct < 8; ++ct)
#pragma unroll
        for (int r = 0; r < 4; ++r) lmax = fmaxf(lmax, acc[ct][r] - kd4[r]);
    } else {
#pragma unroll
      for (int ct = 0; ct < 8; ++ct) {
        int m = cH * 128 + ct * 16 + l15;
#pragma unroll
        for (int r = 0; r < 4; ++r) {
          float kp = __expf(acc[ct][r] - kd4[r] - skv + LN_CK);
          k_prime[((size_t)bh * T_ + t0 + r0 + g4 * 4 + r) * M_ + m] = (f16)kp;
        }
      }
    }
  }
  if (MODE == 0) {
#pragma unroll
    for (int off = 32; off; off >>= 1) lmax = fmaxf(lmax, __shfl_xor(lmax, off));
    if (l == 0) red[w] = lmax;
    __syncthreads();
    if (t == 0) {
      float mm = red[0];
#pragma unroll
      for (int ww = 1; ww < 8; ++ww) mm = fmaxf(mm, red[ww]);
      atomicMax(skb + bh, fkey(mm));
    }
  }
}

// kv partials: kvacc4[c][bh][d][m] = sum over 512 t-rows of kp[t][m]*v[t][d]
// d=64 row is ones (kp_sum); d=65..79 zero. Plain stores (deterministic).
__global__ __launch_bounds__(512) void kv_kernel(
    const float* __restrict__ value, const f16* __restrict__ k_prime,
    float* __restrict__ kvacc4) {
  __shared__ f16 kpT[M_][72];
  __shared__ f16 vT[80][72];
  const int blk = blockIdx.x;  // 24 bh x 4 c
  const int c = blk & 3, bh = blk >> 2;
  const int b = bh / H_, h = bh % H_;
  const int t = threadIdx.x;
  const int w = t >> 6, l = t & 63, l15 = l & 15, g4 = l >> 4;

  for (int idx = t; idx < 16 * 72; idx += 512) {
    int rr = idx / 72, cc = idx % 72;
    vT[64 + rr][cc] = (rr == 0) ? (f16)1.0f : (f16)0.0f;
  }
  f32x4 acc[2][5];
#pragma unroll
  for (int q = 0; q < 2; ++q)
#pragma unroll
    for (int n2 = 0; n2 < 5; ++n2) acc[q][n2] = (f32x4){0.f, 0.f, 0.f, 0.f};

  for (int sc = 0; sc < 8; ++sc) {
    const int tb = c * 512 + sc * 64;
    __syncthreads();
#pragma unroll
    for (int it = 0; it < 2; ++it) {
      int idx = it * 512 + t;
      int m2 = idx & 127, t8 = idx >> 7;
      const f16* gp = k_prime + ((size_t)bh * T_ + tb + t8 * 8) * M_ + m2 * 2;
      f16x8 a0, a1;
#pragma unroll
      for (int r = 0; r < 8; ++r) {
        f16x2 v2 = *(const f16x2*)(gp + (size_t)r * M_);
        a0[r] = v2[0]; a1[r] = v2[1];
      }
      int m0 = m2 * 2;
      *(f16x8*)&kpT[m0][(t8 ^ ((m0 >> 1) & 7)) * 8] = a0;
      *(f16x8*)&kpT[m0 + 1][(t8 ^ (((m0 + 1) >> 1) & 7)) * 8] = a1;
    }
    {
      int d = l, t8 = w;
      const float* gv = value + (((size_t)b * T_ + tb + t8 * 8) * H_ + h) * E_ + d;
      f16x8 a;
#pragma unroll
      for (int r = 0; r < 8; ++r) a[r] = (f16)gv[(size_t)r * H_ * E_];
      *(f16x8*)&vT[d][(t8 ^ ((d >> 1) & 7)) * 8] = a;
    }
    __syncthreads();
#pragma unroll
    for (int kk = 0; kk < 2; ++kk) {
      int u = kk * 4 + g4;
      f16x8 afr[2];
#pragma unroll
      for (int q = 0; q < 2; ++q) {
        int m = (w * 2 + q) * 16 + l15;
        afr[q] = *(const f16x8*)&kpT[m][(u ^ ((m >> 1) & 7)) * 8];
      }
#pragma unroll
      for (int n2 = 0; n2 < 5; ++n2) {
        int d = n2 * 16 + l15;
        f16x8 bfr = *(const f16x8*)&vT[d][(u ^ ((d >> 1) & 7)) * 8];
#pragma unroll
        for (int q = 0; q < 2; ++q) acc[q][n2] = MFMA16(afr[q], bfr, acc[q][n2]);
      }
    }
  }
#pragma unroll
  for (int q = 0; q < 2; ++q)
#pragma unroll
    for (int n2 = 0; n2 < 5; ++n2) {
      int d = n2 * 16 + l15;
      int m0 = (w * 2 + q) * 16 + g4 * 4;
      float4 st = {acc[q][n2][0], acc[q][n2][1], acc[q][n2][2], acc[q][n2][3]};
      *(float4*)(kvacc4 + (size_t)c * PSTRIDE + ((size_t)bh * 80 + d) * M_ + m0) = st;
    }
}

// main: one block per (b,h,n). Non-online: all 3 windows' S and dp in regs.
__global__ __launch_bounds__(512) void main_kernel(
    const float* __restrict__ query, const float* __restrict__ key,
    const float* __restrict__ value, const f16* __restrict__ projh,
    const f16* __restrict__ k_prime, const float* __restrict__ kvacc4,
    const unsigned* __restrict__ skb, float* __restrict__ out) {
  __shared__ f16 qpL[BLK][264];   // q' tile, later dots tile (33792 B)
  __shared__ f16 vTh[BLK][200];   // V^T (3 windows), XOR-swizzled (25600 B)
  __shared__ float sqw[BLK][2], wmax[BLK][2], ps2[BLK][2], ds2[BLK][2];
  __shared__ float qdrow[BLK], qp1row[BLK], efac[BLK], psr[BLK];

  const int blk = blockIdx.x;
  const int nb = blk & (NBLK - 1);
  const int bh = blk >> 5;
  const int b = bh / H_, h = bh % H_;
  const int t0g = nb * BLK;
  const int t = threadIdx.x;
  const int w = t >> 6, l = t & 63, l15 = l & 15, g4 = l >> 4;
  const int rblk = w & 3, cH = w >> 2, r0 = rblk * 16;
  const float s_k = unfkey(skb[bh]);

  int tkw[3];
  bool wvalid[3];
#pragma unroll
  for (int wi = 0; wi < 3; ++wi) {
    int rb = nb - 1 + wi;
    wvalid[wi] = (rb >= 0) && (rb < NBLK);
    tkw[wi] = ((rb < 0) ? 0 : (rb > NBLK - 1 ? NBLK - 1 : rb)) * BLK;
  }

  // ---- stage V^T (3 windows, clamped) ----
  {
    int d = l;
#pragma unroll
    for (int it = 0; it < 3; ++it) {
      int tg = it * 8 + w;                    // 0..23
      int wi = tg >> 3, j = (tg & 7) * 8;
      const float* gv = value + (((size_t)b * T_ + tkw[wi] + j) * H_ + h) * E_ + d;
      f16x8 a;
#pragma unroll
      for (int r = 0; r < 8; ++r) a[r] = (f16)gv[(size_t)r * H_ * E_];
      *(f16x8*)&vTh[d][(tg ^ (d & 7)) * 8] = a;
    }
  }

  // ---- q A-frags + q_diag (shfl) ----
  f16x8 av_q[2];
  {
    float qdl = 0.f;
    const float* gq = query + (((size_t)b * T_ + t0g + r0 + l15) * H_ + h) * E_;
#pragma unroll
    for (int kk = 0; kk < 2; ++kk) {
      int e0 = kk * 32 + g4 * 8;
      float4 a = *(const float4*)(gq + e0);
      float4 bq = *(const float4*)(gq + e0 + 4);
      float x0 = a.x * DN, x1 = a.y * DN, x2 = a.z * DN, x3 = a.w * DN;
      float y0 = bq.x * DN, y1 = bq.y * DN, y2 = bq.z * DN, y3 = bq.w * DN;
      av_q[kk] = (f16x8){(f16)x0, (f16)x1, (f16)x2, (f16)x3,
                         (f16)y0, (f16)y1, (f16)y2, (f16)y3};
      qdl += x0 * x0 + x1 * x1 + x2 * x2 + x3 * x3 + y0 * y0 + y1 * y1 + y2 * y2 + y3 * y3;
    }
    qdl *= 0.5f;
    qdl += __shfl_xor(qdl, 16);
    qdl += __shfl_xor(qdl, 32);
    if (cH == 0 && g4 == 0) qdrow[r0 + l15] = qdl;
  }

  // ---- q_dash GEMM (B from projh global) ----
  f32x4 qdacc[8];
#pragma unroll
  for (int ct = 0; ct < 8; ++ct) qdacc[ct] = (f32x4){0.f, 0.f, 0.f, 0.f};
#pragma unroll
  for (int kk = 0; kk < 2; ++kk)
#pragma unroll
    for (int ct = 0; ct < 8; ++ct) {
      int m = cH * 128 + ct * 16 + l15;
      f16x8 bv = *(const f16x8*)(projh + m * E_ + kk * 32 + g4 * 8);
      qdacc[ct] = MFMA16(av_q[kk], bv, qdacc[ct]);
    }

  // ---- QK (B from key global, inline cvt) ----
  f32x4 sacc[6];
#pragma unroll
  for (int a = 0; a < 6; ++a) sacc[a] = (f32x4){0.f, 0.f, 0.f, 0.f};
#pragma unroll
  for (int wi = 0; wi < 3; ++wi) {
    if (!wvalid[wi]) continue;
#pragma unroll
    for (int q2 = 0; q2 < 2; ++q2) {
      int j = cH * 32 + q2 * 16 + l15;
      const float* gk = key + (((size_t)b * T_ + tkw[wi] + j) * H_ + h) * E_;
#pragma unroll
      for (int kk = 0; kk < 2; ++kk) {
        int e0 = kk * 32 + g4 * 8;
        float4 a = *(const float4*)(gk + e0);
        float4 bk = *(const float4*)(gk + e0 + 4);
        f16x8 bv = (f16x8){(f16)(a.x * DN), (f16)(a.y * DN), (f16)(a.z * DN), (f16)(a.w * DN),
                           (f16)(bk.x * DN), (f16)(bk.y * DN), (f16)(bk.z * DN), (f16)(bk.w * DN)};
        sacc[wi * 2 + q2] = MFMA16(av_q[kk], bv, sacc[wi * 2 + q2]);
      }
    }
  }

  // ---- q_dash row max -> sqw ----
#pragma unroll
  for (int r = 0; r < 4; ++r) {
    float mx = qdacc[0][r];
#pragma unroll
    for (int ct = 1; ct < 8; ++ct) mx = fmaxf(mx, qdacc[ct][r]);
#pragma unroll
    for (int off = 1; off <= 8; off <<= 1) mx = fmaxf(mx, __shfl_xor(mx, off));
    if (l15 == 0) sqw[r0 + g4 * 4 + r][cH] = mx;
  }
  __syncthreads();  // B1: vTh, sqw, qdrow ready

  // ---- q' = exp(qdash - s_q + LN_CQ) -> qpL ----
  {
    float sq4[4];
#pragma unroll
    for (int r = 0; r < 4; ++r) {
      int row = r0 + g4 * 4 + r;
      sq4[r] = fmaxf(sqw[row][0], sqw[row][1]);
    }
#pragma unroll
    for (int ct = 0; ct < 8; ++ct) {
      int m = cH * 128 + ct * 16 + l15;
#pragma unroll
      for (int r = 0; r < 4; ++r)
        qpL[r0 + g4 * 4 + r][m] = (f16)__expf(qdacc[ct][r] - sq4[r] + LN_CQ);
    }
  }
  __syncthreads();  // B2: qpL ready

  // ---- qkv GEMM (B = sum of 4 kvacc partials) + dp GEMMs (B from k_prime) ----
  f32x4 dacc[6], qkv[3];
#pragma unroll
  for (int a = 0; a < 6; ++a) dacc[a] = (f32x4){0.f, 0.f, 0.f, 0.f};
#pragma unroll
  for (int q2 = 0; q2 < 3; ++q2) qkv[q2] = (f32x4){0.f, 0.f, 0.f, 0.f};
  const int nqt = (cH == 0) ? 3 : 2;
#pragma unroll
  for (int kk = 0; kk < 8; ++kk) {
    f16x8 av = *(const f16x8*)&qpL[r0 + l15][kk * 32 + g4 * 8];
    for (int q2 = 0; q2 < nqt; ++q2) {
      int d0 = (q2 < 2) ? (cH * 32 + q2 * 16 + l15) : (64 + l15);
      const float* kb = kvacc4 + ((size_t)bh * 80 + d0) * M_ + kk * 32 + g4 * 8;
      float4 f0 = {0.f, 0.f, 0.f, 0.f}, f1 = {0.f, 0.f, 0.f, 0.f};
#pragma unroll
      for (int p = 0; p < 4; ++p) {
        const float* kp2 = kb + (size_t)p * PSTRIDE;
        float4 u0 = *(const float4*)kp2;
        float4 u1 = *(const float4*)(kp2 + 4);
        f0.x += u0.x; f0.y += u0.y; f0.z += u0.z; f0.w += u0.w;
        f1.x += u1.x; f1.y += u1.y; f1.z += u1.z; f1.w += u1.w;
      }
      f16x8 bv = (f16x8){(f16)f0.x, (f16)f0.y, (f16)f0.z, (f16)f0.w,
                         (f16)f1.x, (f16)f1.y, (f16)f1.z, (f16)f1.w};
      qkv[q2] = MFMA16(av, bv, qkv[q2]);
    }
#pragma unroll
    for (int wi = 0; wi < 3; ++wi) {
      if (!wvalid[wi]) continue;
#pragma unroll
      for (int q2 = 0; q2 < 2; ++q2) {
        int j = cH * 32 + q2 * 16 + l15;
        f16x8 bv = *(const f16x8*)(k_prime + ((size_t)bh * T_ + tkw[wi] + j) * M_ + kk * 32 + g4 * 8);
        dacc[wi * 2 + q2] = MFMA16(av, bv, dacc[wi * 2 + q2]);
      }
    }
  }

  // ---- QK row max + qp1 ----
#pragma unroll
  for (int r = 0; r < 4; ++r) {
    float mx = -3.0e38f;
#pragma unroll
    for (int a = 0; a < 6; ++a)
      if (wvalid[a >> 1]) mx = fmaxf(mx, sacc[a][r]);
#pragma unroll
    for (int off = 1; off <= 8; off <<= 1) mx = fmaxf(mx, __shfl_xor(mx, off));
    if (l15 == 0) wmax[r0 + g4 * 4 + r][cH] = mx;
  }
  if (cH == 0 && l15 == 0) {
#pragma unroll
    for (int r = 0; r < 4; ++r) qp1row[r0 + g4 * 4 + r] = qkv[2][r];
  }
  __syncthreads();  // B3: wmax, qp1row

  // ---- exp + row sums (sacc := exp(S - m_row)) ----
  {
    float m4[4];
#pragma unroll
    for (int r = 0; r < 4; ++r) {
      int row = r0 + g4 * 4 + r;
      m4[r] = fmaxf(wmax[row][0], wmax[row][1]);
    }
    float psl[4] = {0.f, 0.f, 0.f, 0.f}, dsl[4] = {0.f, 0.f, 0.f, 0.f};
#pragma unroll
    for (int a = 0; a < 6; ++a) {
      if (wvalid[a >> 1]) {
#pragma unroll
        for (int r = 0; r < 4; ++r) {
          sacc[a][r] = __expf(sacc[a][r] - m4[r]);
          psl[r] += sacc[a][r];
          dsl[r] += dacc[a][r];
        }
      } else {
#pragma unroll
        for (int r = 0; r < 4; ++r) sacc[a][r] = 0.f;
      }
    }
#pragma unroll
    for (int r = 0; r < 4; ++r) {
#pragma unroll
      for (int off = 1; off <= 8; off <<= 1) {
        psl[r] += __shfl_xor(psl[r], off);
        dsl[r] += __shfl_xor(dsl[r], off);
      }
      if (l15 == 0) {
        int row = r0 + g4 * 4 + r;
        ps2[row][cH] = psl[r];
        ds2[row][cH] = dsl[r];
      }
    }
  }
  __syncthreads();  // B4

  if (t < BLK) {
    float mrow = fmaxf(wmax[t][0], wmax[t][1]);
    float lse = mrow + __logf(ps2[t][0] + ps2[t][1]);
    float dsum = ds2[t][0] + ds2[t][1];
    float sqrow = fmaxf(sqw[t][0], sqw[t][1]);
    float plsC = sqrow - qdrow[t] - HALF_LOG_M + s_k - HALF_LOG_M - LN_CQ - LN_CK;
    float lr = __logf(fmaxf(qp1row[t] - dsum, 1e-24f)) + plsC;
    float mm = fmaxf(lse, lr);
    float ln = mm + __logf(__expf(lse - mm) + __expf(lr - mm));
    efac[t] = __expf(mrow - ln);
    psr[t] = __expf(plsC - ln);
  }
  __syncthreads();  // B5

  // ---- dots tile (reuse qpL) ----
  float ef4[4], ps4[4];
#pragma unroll
  for (int r = 0; r < 4; ++r) {
    int row = r0 + g4 * 4 + r;
    ef4[r] = efac[row];
    ps4[r] = psr[row];
  }
#pragma unroll
  for (int a = 0; a < 6; ++a) {
    int c = (a >> 1) * 64 + cH * 32 + (a & 1) * 16 + l15;
#pragma unroll
    for (int r = 0; r < 4; ++r)
      qpL[r0 + g4 * 4 + r][c] = (f16)(sacc[a][r] * ef4[r] - dacc[a][r] * ps4[r]);
  }
  __syncthreads();  // B6

  // ---- PV over K=192 ----
  f32x4 oacc[2];
  oacc[0] = oacc[1] = (f32x4){0.f, 0.f, 0.f, 0.f};
#pragma unroll
  for (int kk = 0; kk < 6; ++kk) {
    f16x8 av = *(const f16x8*)&qpL[r0 + l15][kk * 32 + g4 * 8];
    int u = kk * 4 + g4;
#pragma unroll
    for (int q2 = 0; q2 < 2; ++q2) {
      int d = cH * 32 + q2 * 16 + l15;
      f16x8 bv = *(const f16x8*)&vTh[d][(u ^ (d & 7)) * 8];
      oacc[q2] = MFMA16(av, bv, oacc[q2]);
    }
  }

  // ---- out = dots.V + qkv*ps ----
#pragma unroll
  for (int q2 = 0; q2 < 2; ++q2) {
    int d = cH * 32 + q2 * 16 + l15;
#pragma unroll
    for (int r = 0; r < 4; ++r) {
      int row = r0 + g4 * 4 + r;
      out[(((size_t)b * T_ + t0g + row) * H_ + h) * E_ + d] =
          oacc[q2][r] + qkv[q2][r] * ps4[r];
    }
  }
}

extern "C" void kernel_launch(void* const* d_in, const int* in_sizes, int n_in,
                              void* d_out, int out_size, void* d_ws, size_t ws_size,
                              hipStream_t stream) {
  const float* query = (const float*)d_in[0];
  const float* key   = (const float*)d_in[1];
  const float* value = (const float*)d_in[2];
  const float* proj  = (const float*)d_in[3];
  float* out = (float*)d_out;

  char* ws = (char*)d_ws;
  unsigned* skb = (unsigned*)ws;
  f16* projh = (f16*)(ws + 256);
  f16* k_prime = (f16*)(ws + 33024);
  float* kvacc4 = (float*)(ws + 25198848);

  init_ws<<<64, 256, 0, stream>>>(skb, projh, proj);
  kshift_kernel<0><<<B_ * H_ * 8, 512, 0, stream>>>(key, projh, skb, nullptr);
  kshift_kernel<1><<<B_ * H_ * 8, 512, 0, stream>>>(key, projh, skb, k_prime);
  kv_kernel<<<B_ * H_ * 4, 512, 0, stream>>>(value, k_prime, kvacc4);
  main_kernel<<<B_ * H_ * NBLK, 512, 0, stream>>>(query, key, value, projh,
                                                  k_prime, kvacc4, skb, out);
}

// Round 4
// 154.335 us; speedup vs baseline: 1.5582x; 1.5582x over previous
//
#include <hip/hip_runtime.h>

#define B_ 2
#define T_ 2048
#define H_ 12
#define E_ 64
#define M_ 256
#define BLK 64
#define NBLK 32

typedef _Float16 f16;
typedef f16 f16x2 __attribute__((ext_vector_type(2)));
typedef f16 f16x4 __attribute__((ext_vector_type(4)));
typedef f16 f16x8 __attribute__((ext_vector_type(8)));
typedef float f32x4 __attribute__((ext_vector_type(4)));

#define MFMA16(Av, Bv, Cv) __builtin_amdgcn_mfma_f32_16x16x32_f16(Av, Bv, Cv, 0, 0, 0)

constexpr float DN = 0.35355339059327373f;        // sqrt(temp)
constexpr float HALF_LOG_M = 2.7725887222397811f; // 0.5*ln(256)
constexpr float LN_CQ = 5.545177444479562f;       // ln(256): q' scale (denormal guard)
constexpr float LN_CK = 2.772588722239781f;       // ln(16):  k' scale

__device__ __forceinline__ unsigned fkey(float f) {
  unsigned u = __float_as_uint(f);
  return (u & 0x80000000u) ? ~u : (u | 0x80000000u);
}
__device__ __forceinline__ float unfkey(unsigned k) {
  return (k & 0x80000000u) ? __uint_as_float(k & 0x7fffffffu) : __uint_as_float(~k);
}

// ---------------- workspace layout (bytes) ----------------
// 0         : skb    uint[24]                    (pad 256)
// 256       : projh  f16 [256][64]      32768 -> 33024
// 33024     : k_prime f16 [24][2048][256] 25165824 -> 25198848
// 25198848  : dots   f16 [24][2048][192] 18874368 -> 44073216
// 44073216  : kvacc4 f32 [4][24][68][256] 6684672 -> 50757888
// 50757888  : kvT    f16 [24][80][256]     983040 -> 51740928  (< proven 52.13 MB)
#define PSTRIDEF 417792  // 24*68*256 floats per partial

__global__ void init_ws(unsigned* __restrict__ skb, f16* __restrict__ projh,
                        const float* __restrict__ proj) {
  int i = blockIdx.x * blockDim.x + threadIdx.x;
  if (i < B_ * H_) skb[i] = 0u;
  if (i < M_ * E_) projh[i] = (f16)proj[i];
}

// MODE 0: global max of k_shift -> skb (atomicMax)
// MODE 1: k_prime = 16*exp(k_shift - s_k) -> f16 global
template <int MODE>
__global__ __launch_bounds__(512) void kshift_kernel(
    const float* __restrict__ key, const f16* __restrict__ projh,
    unsigned* __restrict__ skb, f16* __restrict__ k_prime) {
  __shared__ float red[8];
  const int blk = blockIdx.x;  // 24 bh x 8 chunks
  const int chunk = blk & 7, bh = blk >> 3;
  const int b = bh / H_, h = bh % H_;
  const int t = threadIdx.x;
  const int w = t >> 6, l = t & 63, l15 = l & 15, g4 = l >> 4;
  const int rblk = w & 3, cH = w >> 2, r0 = rblk * 16;
  const float skv = (MODE == 1) ? unfkey(skb[bh]) : 0.f;
  float lmax = -3.0e38f;

  for (int ti = 0; ti < 4; ++ti) {
    const int t0 = chunk * 256 + ti * 64;
    f16x8 avk[2];
    float kdl = 0.f;
    {
      const float* gk = key + (((size_t)b * T_ + t0 + r0 + l15) * H_ + h) * E_;
#pragma unroll
      for (int kk = 0; kk < 2; ++kk) {
        int e0 = kk * 32 + g4 * 8;
        float4 a = *(const float4*)(gk + e0);
        float4 bq = *(const float4*)(gk + e0 + 4);
        float x0 = a.x * DN, x1 = a.y * DN, x2 = a.z * DN, x3 = a.w * DN;
        float y0 = bq.x * DN, y1 = bq.y * DN, y2 = bq.z * DN, y3 = bq.w * DN;
        avk[kk] = (f16x8){(f16)x0, (f16)x1, (f16)x2, (f16)x3,
                          (f16)y0, (f16)y1, (f16)y2, (f16)y3};
        kdl += x0 * x0 + x1 * x1 + x2 * x2 + x3 * x3 + y0 * y0 + y1 * y1 + y2 * y2 + y3 * y3;
      }
      kdl *= 0.5f;
      kdl += __shfl_xor(kdl, 16);
      kdl += __shfl_xor(kdl, 32);
    }
    f32x4 acc[8];
#pragma unroll
    for (int ct = 0; ct < 8; ++ct) acc[ct] = (f32x4){0.f, 0.f, 0.f, 0.f};
#pragma unroll
    for (int kk = 0; kk < 2; ++kk)
#pragma unroll
      for (int ct = 0; ct < 8; ++ct) {
        int m = cH * 128 + ct * 16 + l15;
        f16x8 bv = *(const f16x8*)(projh + m * E_ + kk * 32 + g4 * 8);
        acc[ct] = MFMA16(avk[kk], bv, acc[ct]);
      }
    float kd4[4];
#pragma unroll
    for (int r = 0; r < 4; ++r) kd4[r] = __shfl(kdl, (l & 48) + g4 * 4 + r);
    if (MODE == 0) {
#pragma unroll
      for (int ct = 0; ct < 8; ++ct)
#pragma unroll
        for (int r = 0; r < 4; ++r) lmax = fmaxf(lmax, acc[ct][r] - kd4[r]);
    } else {
#pragma unroll
      for (int ct = 0; ct < 8; ++ct) {
        int m = cH * 128 + ct * 16 + l15;
#pragma unroll
        for (int r = 0; r < 4; ++r) {
          float kp = __expf(acc[ct][r] - kd4[r] - skv + LN_CK);
          k_prime[((size_t)bh * T_ + t0 + r0 + g4 * 4 + r) * M_ + m] = (f16)kp;
        }
      }
    }
  }
  if (MODE == 0) {
#pragma unroll
    for (int off = 32; off; off >>= 1) lmax = fmaxf(lmax, __shfl_xor(lmax, off));
    if (l == 0) red[w] = lmax;
    __syncthreads();
    if (t == 0) {
      float mm = red[0];
#pragma unroll
      for (int ww = 1; ww < 8; ++ww) mm = fmaxf(mm, red[ww]);
      atomicMax(skb + bh, fkey(mm));
    }
  }
}

// kv partials: kvacc4[c][bh][d][m] (d<68) = sum over 512 t-rows of kp[t][m]*v[t][d]
// d=64 row is ones (kp_sum). Plain stores (deterministic).
__global__ __launch_bounds__(512) void kv_kernel(
    const float* __restrict__ value, const f16* __restrict__ k_prime,
    float* __restrict__ kvacc4) {
  __shared__ f16 kpT[M_][72];
  __shared__ f16 vT[80][72];
  const int blk = blockIdx.x;  // 24 bh x 4 c
  const int c = blk & 3, bh = blk >> 2;
  const int b = bh / H_, h = bh % H_;
  const int t = threadIdx.x;
  const int w = t >> 6, l = t & 63, l15 = l & 15, g4 = l >> 4;

  for (int idx = t; idx < 16 * 72; idx += 512) {
    int rr = idx / 72, cc = idx % 72;
    vT[64 + rr][cc] = (rr == 0) ? (f16)1.0f : (f16)0.0f;
  }
  f32x4 acc[2][5];
#pragma unroll
  for (int q = 0; q < 2; ++q)
#pragma unroll
    for (int n2 = 0; n2 < 5; ++n2) acc[q][n2] = (f32x4){0.f, 0.f, 0.f, 0.f};

  for (int sc = 0; sc < 8; ++sc) {
    const int tb = c * 512 + sc * 64;
    __syncthreads();
#pragma unroll
    for (int it = 0; it < 2; ++it) {
      int idx = it * 512 + t;
      int m2 = idx & 127, t8 = idx >> 7;
      const f16* gp = k_prime + ((size_t)bh * T_ + tb + t8 * 8) * M_ + m2 * 2;
      f16x8 a0, a1;
#pragma unroll
      for (int r = 0; r < 8; ++r) {
        f16x2 v2 = *(const f16x2*)(gp + (size_t)r * M_);
        a0[r] = v2[0]; a1[r] = v2[1];
      }
      int m0 = m2 * 2;
      *(f16x8*)&kpT[m0][(t8 ^ ((m0 >> 1) & 7)) * 8] = a0;
      *(f16x8*)&kpT[m0 + 1][(t8 ^ (((m0 + 1) >> 1) & 7)) * 8] = a1;
    }
    {
      int d = l, t8 = w;
      const float* gv = value + (((size_t)b * T_ + tb + t8 * 8) * H_ + h) * E_ + d;
      f16x8 a;
#pragma unroll
      for (int r = 0; r < 8; ++r) a[r] = (f16)gv[(size_t)r * H_ * E_];
      *(f16x8*)&vT[d][(t8 ^ ((d >> 1) & 7)) * 8] = a;
    }
    __syncthreads();
#pragma unroll
    for (int kk = 0; kk < 2; ++kk) {
      int u = kk * 4 + g4;
      f16x8 afr[2];
#pragma unroll
      for (int q = 0; q < 2; ++q) {
        int m = (w * 2 + q) * 16 + l15;
        afr[q] = *(const f16x8*)&kpT[m][(u ^ ((m >> 1) & 7)) * 8];
      }
#pragma unroll
      for (int n2 = 0; n2 < 5; ++n2) {
        int d = n2 * 16 + l15;
        f16x8 bfr = *(const f16x8*)&vT[d][(u ^ ((d >> 1) & 7)) * 8];
#pragma unroll
        for (int q = 0; q < 2; ++q) acc[q][n2] = MFMA16(afr[q], bfr, acc[q][n2]);
      }
    }
  }
#pragma unroll
  for (int q = 0; q < 2; ++q)
#pragma unroll
    for (int n2 = 0; n2 < 5; ++n2) {
      int d = n2 * 16 + l15;
      if (d < 68) {
        int m0 = (w * 2 + q) * 16 + g4 * 4;
        float4 st = {acc[q][n2][0], acc[q][n2][1], acc[q][n2][2], acc[q][n2][3]};
        *(float4*)(kvacc4 + (size_t)c * PSTRIDEF + ((size_t)bh * 68 + d) * M_ + m0) = st;
      }
    }
}

// reduce 4 partials -> kvT f16 [24][80][256] (rows 68..79 zero)
__global__ __launch_bounds__(256) void kvred_kernel(
    const float* __restrict__ kvacc4, f16* __restrict__ kvT) {
  int idx = blockIdx.x * 256 + threadIdx.x;  // 480 blocks -> 122880 threads
  int m0 = (idx & 63) * 4;
  int rd = idx >> 6;          // bh*80 + d
  int bh = rd / 80, d = rd - bh * 80;
  float4 s = {0.f, 0.f, 0.f, 0.f};
  if (d < 68) {
    const float* p = kvacc4 + ((size_t)bh * 68 + d) * M_ + m0;
#pragma unroll
    for (int c = 0; c < 4; ++c) {
      float4 u = *(const float4*)(p + (size_t)c * PSTRIDEF);
      s.x += u.x; s.y += u.y; s.z += u.z; s.w += u.w;
    }
  }
  f16x4 hv = {(f16)s.x, (f16)s.y, (f16)s.z, (f16)s.w};
  *(f16x4*)(kvT + ((size_t)bh * 80 + d) * M_ + m0) = hv;
}

// dots_kernel: per (b,h,n). Computes q',dp,qkv,QK,stats; writes dots f16 tile
// and the low-rank term (qkv*psr) directly into out (overwrite).
__global__ __launch_bounds__(512) void dots_kernel(
    const float* __restrict__ query, const float* __restrict__ key,
    const f16* __restrict__ projh, const f16* __restrict__ k_prime,
    const f16* __restrict__ kvT, const unsigned* __restrict__ skb,
    f16* __restrict__ dots, float* __restrict__ out) {
  __shared__ f16 qpL[BLK][264];   // q' tile (33792 B)
  __shared__ float wmaxq[BLK][2], wmax[BLK][2], ps2[BLK][2], ds2[BLK][2];
  __shared__ float qdrow[BLK], qp1row[BLK], efac[BLK], psr[BLK];

  const int blk = blockIdx.x;
  const int nb = blk & (NBLK - 1);
  const int bh = blk >> 5;
  const int b = bh / H_, h = bh % H_;
  const int t0g = nb * BLK;
  const int t = threadIdx.x;
  const int w = t >> 6, l = t & 63, l15 = l & 15, g4 = l >> 4;
  const int rblk = w & 3, cH = w >> 2, r0 = rblk * 16;
  const float s_k = unfkey(skb[bh]);

  int tkw[3];
  bool wvalid[3];
#pragma unroll
  for (int wi = 0; wi < 3; ++wi) {
    int rb = nb - 1 + wi;
    wvalid[wi] = (rb >= 0) && (rb < NBLK);
    tkw[wi] = ((rb < 0) ? 0 : (rb > NBLK - 1 ? NBLK - 1 : rb)) * BLK;
  }

  // ---- q A-frags + q_diag (shfl) ----
  f16x8 av_q[2];
  {
    float qdl = 0.f;
    const float* gq = query + (((size_t)b * T_ + t0g + r0 + l15) * H_ + h) * E_;
#pragma unroll
    for (int kk = 0; kk < 2; ++kk) {
      int e0 = kk * 32 + g4 * 8;
      float4 a = *(const float4*)(gq + e0);
      float4 bq = *(const float4*)(gq + e0 + 4);
      float x0 = a.x * DN, x1 = a.y * DN, x2 = a.z * DN, x3 = a.w * DN;
      float y0 = bq.x * DN, y1 = bq.y * DN, y2 = bq.z * DN, y3 = bq.w * DN;
      av_q[kk] = (f16x8){(f16)x0, (f16)x1, (f16)x2, (f16)x3,
                         (f16)y0, (f16)y1, (f16)y2, (f16)y3};
      qdl += x0 * x0 + x1 * x1 + x2 * x2 + x3 * x3 + y0 * y0 + y1 * y1 + y2 * y2 + y3 * y3;
    }
    qdl *= 0.5f;
    qdl += __shfl_xor(qdl, 16);
    qdl += __shfl_xor(qdl, 32);
    if (cH == 0 && g4 == 0) qdrow[r0 + l15] = qdl;
  }

  // ---- q_dash GEMM (B from projh global) ----
  f32x4 qdacc[8];
#pragma unroll
  for (int ct = 0; ct < 8; ++ct) qdacc[ct] = (f32x4){0.f, 0.f, 0.f, 0.f};
#pragma unroll
  for (int kk = 0; kk < 2; ++kk)
#pragma unroll
    for (int ct = 0; ct < 8; ++ct) {
      int m = cH * 128 + ct * 16 + l15;
      f16x8 bv = *(const f16x8*)(projh + m * E_ + kk * 32 + g4 * 8);
      qdacc[ct] = MFMA16(av_q[kk], bv, qdacc[ct]);
    }

  // ---- q_dash row max -> wmaxq ----
#pragma unroll
  for (int r = 0; r < 4; ++r) {
    float mx = qdacc[0][r];
#pragma unroll
    for (int ct = 1; ct < 8; ++ct) mx = fmaxf(mx, qdacc[ct][r]);
#pragma unroll
    for (int off = 1; off <= 8; off <<= 1) mx = fmaxf(mx, __shfl_xor(mx, off));
    if (l15 == 0) wmaxq[r0 + g4 * 4 + r][cH] = mx;
  }
  __syncthreads();  // B1

  // ---- q' = exp(qdash - s_q + LN_CQ) -> qpL ----
  {
    float sq4[4];
#pragma unroll
    for (int r = 0; r < 4; ++r) {
      int row = r0 + g4 * 4 + r;
      sq4[r] = fmaxf(wmaxq[row][0], wmaxq[row][1]);
    }
#pragma unroll
    for (int ct = 0; ct < 8; ++ct) {
      int m = cH * 128 + ct * 16 + l15;
#pragma unroll
      for (int r = 0; r < 4; ++r)
        qpL[r0 + g4 * 4 + r][m] = (f16)__expf(qdacc[ct][r] - sq4[r] + LN_CQ);
    }
  }
  __syncthreads();  // B2

  // ---- q' A-frags (loaded once, reused for dp + qkv) ----
  f16x8 av_p[8];
#pragma unroll
  for (int kk = 0; kk < 8; ++kk)
    av_p[kk] = *(const f16x8*)&qpL[r0 + l15][kk * 32 + g4 * 8];

  // ---- dp GEMMs (B from k_prime) + qkv GEMM (B from kvT f16) ----
  f32x4 dacc[6], qkv[3];
#pragma unroll
  for (int a = 0; a < 6; ++a) dacc[a] = (f32x4){0.f, 0.f, 0.f, 0.f};
#pragma unroll
  for (int q2 = 0; q2 < 3; ++q2) qkv[q2] = (f32x4){0.f, 0.f, 0.f, 0.f};
  const int nqt = (cH == 0) ? 3 : 2;
#pragma unroll
  for (int kk = 0; kk < 8; ++kk) {
    for (int q2 = 0; q2 < nqt; ++q2) {
      int d0 = (q2 < 2) ? (cH * 32 + q2 * 16 + l15) : (64 + l15);
      f16x8 bv = *(const f16x8*)(kvT + ((size_t)bh * 80 + d0) * M_ + kk * 32 + g4 * 8);
      qkv[q2] = MFMA16(av_p[kk], bv, qkv[q2]);
    }
#pragma unroll
    for (int wi = 0; wi < 3; ++wi) {
      if (!wvalid[wi]) continue;
#pragma unroll
      for (int q2 = 0; q2 < 2; ++q2) {
        int j = cH * 32 + q2 * 16 + l15;
        f16x8 bv = *(const f16x8*)(k_prime + ((size_t)bh * T_ + tkw[wi] + j) * M_ + kk * 32 + g4 * 8);
        dacc[wi * 2 + q2] = MFMA16(av_p[kk], bv, dacc[wi * 2 + q2]);
      }
    }
  }

  // ---- QK (B from key global, inline cvt) ----
  f32x4 sacc[6];
#pragma unroll
  for (int a = 0; a < 6; ++a) sacc[a] = (f32x4){0.f, 0.f, 0.f, 0.f};
#pragma unroll
  for (int wi = 0; wi < 3; ++wi) {
    if (!wvalid[wi]) continue;
#pragma unroll
    for (int q2 = 0; q2 < 2; ++q2) {
      int j = cH * 32 + q2 * 16 + l15;
      const float* gk = key + (((size_t)b * T_ + tkw[wi] + j) * H_ + h) * E_;
#pragma unroll
      for (int kk = 0; kk < 2; ++kk) {
        int e0 = kk * 32 + g4 * 8;
        float4 a = *(const float4*)(gk + e0);
        float4 bk = *(const float4*)(gk + e0 + 4);
        f16x8 bv = (f16x8){(f16)(a.x * DN), (f16)(a.y * DN), (f16)(a.z * DN), (f16)(a.w * DN),
                           (f16)(bk.x * DN), (f16)(bk.y * DN), (f16)(bk.z * DN), (f16)(bk.w * DN)};
        sacc[wi * 2 + q2] = MFMA16(av_q[kk], bv, sacc[wi * 2 + q2]);
      }
    }
  }

  // ---- QK row max + qp1 ----
#pragma unroll
  for (int r = 0; r < 4; ++r) {
    float mx = -3.0e38f;
#pragma unroll
    for (int a = 0; a < 6; ++a)
      if (wvalid[a >> 1]) mx = fmaxf(mx, sacc[a][r]);
#pragma unroll
    for (int off = 1; off <= 8; off <<= 1) mx = fmaxf(mx, __shfl_xor(mx, off));
    if (l15 == 0) wmax[r0 + g4 * 4 + r][cH] = mx;
  }
  if (cH == 0 && l15 == 0) {
#pragma unroll
    for (int r = 0; r < 4; ++r) qp1row[r0 + g4 * 4 + r] = qkv[2][r];
  }
  __syncthreads();  // B3

  // ---- exp + row sums ----
  {
    float m4[4];
#pragma unroll
    for (int r = 0; r < 4; ++r) {
      int row = r0 + g4 * 4 + r;
      m4[r] = fmaxf(wmax[row][0], wmax[row][1]);
    }
    float psl[4] = {0.f, 0.f, 0.f, 0.f}, dsl[4] = {0.f, 0.f, 0.f, 0.f};
#pragma unroll
    for (int a = 0; a < 6; ++a) {
      if (wvalid[a >> 1]) {
#pragma unroll
        for (int r = 0; r < 4; ++r) {
          sacc[a][r] = __expf(sacc[a][r] - m4[r]);
          psl[r] += sacc[a][r];
          dsl[r] += dacc[a][r];
        }
      } else {
#pragma unroll
        for (int r = 0; r < 4; ++r) sacc[a][r] = 0.f;
      }
    }
#pragma unroll
    for (int r = 0; r < 4; ++r) {
#pragma unroll
      for (int off = 1; off <= 8; off <<= 1) {
        psl[r] += __shfl_xor(psl[r], off);
        dsl[r] += __shfl_xor(dsl[r], off);
      }
      if (l15 == 0) {
        int row = r0 + g4 * 4 + r;
        ps2[row][cH] = psl[r];
        ds2[row][cH] = dsl[r];
      }
    }
  }
  __syncthreads();  // B4

  if (t < BLK) {
    float mrow = fmaxf(wmax[t][0], wmax[t][1]);
    float lse = mrow + __logf(ps2[t][0] + ps2[t][1]);
    float dsum = ds2[t][0] + ds2[t][1];
    float sqrow = fmaxf(wmaxq[t][0], wmaxq[t][1]);
    float plsC = sqrow - qdrow[t] - HALF_LOG_M + s_k - HALF_LOG_M - LN_CQ - LN_CK;
    float lr = __logf(fmaxf(qp1row[t] - dsum, 1e-24f)) + plsC;
    float mm = fmaxf(lse, lr);
    float ln = mm + __logf(__expf(lse - mm) + __expf(lr - mm));
    efac[t] = __expf(mrow - ln);
    psr[t] = __expf(plsC - ln);
  }
  __syncthreads();  // B5

  // ---- write dots tile (f16 global) + low-rank term into out ----
  float ef4[4], ps4[4];
#pragma unroll
  for (int r = 0; r < 4; ++r) {
    int row = r0 + g4 * 4 + r;
    ef4[r] = efac[row];
    ps4[r] = psr[row];
  }
  f16* drow = dots + ((size_t)bh * T_ + t0g) * 192;
#pragma unroll
  for (int a = 0; a < 6; ++a) {
    int cc = (a >> 1) * 64 + cH * 32 + (a & 1) * 16 + l15;
#pragma unroll
    for (int r = 0; r < 4; ++r)
      drow[(size_t)(r0 + g4 * 4 + r) * 192 + cc] =
          (f16)(sacc[a][r] * ef4[r] - dacc[a][r] * ps4[r]);
  }
#pragma unroll
  for (int q2 = 0; q2 < 2; ++q2) {
    int d = cH * 32 + q2 * 16 + l15;
#pragma unroll
    for (int r = 0; r < 4; ++r) {
      int row = r0 + g4 * 4 + r;
      out[(((size_t)b * T_ + t0g + row) * H_ + h) * E_ + d] = qkv[q2][r] * ps4[r];
    }
  }
}

// pv_kernel: out += dots . V^T  (dots A-frags straight from global/L2)
__global__ __launch_bounds__(512) void pv_kernel(
    const float* __restrict__ value, const f16* __restrict__ dots,
    float* __restrict__ out) {
  __shared__ f16 vTh[BLK][200];  // 25600 B

  const int blk = blockIdx.x;
  const int nb = blk & (NBLK - 1);
  const int bh = blk >> 5;
  const int b = bh / H_, h = bh % H_;
  const int t0g = nb * BLK;
  const int t = threadIdx.x;
  const int w = t >> 6, l = t & 63, l15 = l & 15, g4 = l >> 4;
  const int rblk = w & 3, cH = w >> 2, r0 = rblk * 16;

  int tkw[3];
#pragma unroll
  for (int wi = 0; wi < 3; ++wi) {
    int rb = nb - 1 + wi;
    tkw[wi] = ((rb < 0) ? 0 : (rb > NBLK - 1 ? NBLK - 1 : rb)) * BLK;
  }

  // stage V^T (3 windows, clamped; invalid windows have dots==0)
  {
    int d = l;
#pragma unroll
    for (int it = 0; it < 3; ++it) {
      int tg = it * 8 + w;  // 0..23
      int wi = tg >> 3, j = (tg & 7) * 8;
      const float* gv = value + (((size_t)b * T_ + tkw[wi] + j) * H_ + h) * E_ + d;
      f16x8 a;
#pragma unroll
      for (int r = 0; r < 8; ++r) a[r] = (f16)gv[(size_t)r * H_ * E_];
      *(f16x8*)&vTh[d][(tg ^ (d & 7)) * 8] = a;
    }
  }
  __syncthreads();

  f32x4 oacc[2];
  oacc[0] = oacc[1] = (f32x4){0.f, 0.f, 0.f, 0.f};
  const f16* drow = dots + ((size_t)bh * T_ + t0g + r0 + l15) * 192;
#pragma unroll
  for (int kk = 0; kk < 6; ++kk) {
    f16x8 av = *(const f16x8*)(drow + kk * 32 + g4 * 8);
    int u = kk * 4 + g4;
#pragma unroll
    for (int q2 = 0; q2 < 2; ++q2) {
      int d = cH * 32 + q2 * 16 + l15;
      f16x8 bv = *(const f16x8*)&vTh[d][(u ^ (d & 7)) * 8];
      oacc[q2] = MFMA16(av, bv, oacc[q2]);
    }
  }

#pragma unroll
  for (int q2 = 0; q2 < 2; ++q2) {
    int d = cH * 32 + q2 * 16 + l15;
#pragma unroll
    for (int r = 0; r < 4; ++r) {
      int row = r0 + g4 * 4 + r;
      size_t oidx = (((size_t)b * T_ + t0g + row) * H_ + h) * E_ + d;
      out[oidx] += oacc[q2][r];
    }
  }
}

extern "C" void kernel_launch(void* const* d_in, const int* in_sizes, int n_in,
                              void* d_out, int out_size, void* d_ws, size_t ws_size,
                              hipStream_t stream) {
  const float* query = (const float*)d_in[0];
  const float* key   = (const float*)d_in[1];
  const float* value = (const float*)d_in[2];
  const float* proj  = (const float*)d_in[3];
  float* out = (float*)d_out;

  char* ws = (char*)d_ws;
  unsigned* skb = (unsigned*)ws;
  f16* projh = (f16*)(ws + 256);
  f16* k_prime = (f16*)(ws + 33024);
  f16* dots = (f16*)(ws + 25198848);
  float* kvacc4 = (float*)(ws + 44073216);
  f16* kvT = (f16*)(ws + 50757888);

  init_ws<<<64, 256, 0, stream>>>(skb, projh, proj);
  kshift_kernel<0><<<B_ * H_ * 8, 512, 0, stream>>>(key, projh, skb, nullptr);
  kshift_kernel<1><<<B_ * H_ * 8, 512, 0, stream>>>(key, projh, skb, k_prime);
  kv_kernel<<<B_ * H_ * 4, 512, 0, stream>>>(value, k_prime, kvacc4);
  kvred_kernel<<<480, 256, 0, stream>>>(kvacc4, kvT);
  dots_kernel<<<B_ * H_ * NBLK, 512, 0, stream>>>(query, key, projh, k_prime,
                                                  kvT, skb, dots, out);
  pv_kernel<<<B_ * H_ * NBLK, 512, 0, stream>>>(value, dots, out);
}

// Round 5
// 139.903 us; speedup vs baseline: 1.7189x; 1.1032x over previous
//
#include <hip/hip_runtime.h>

#define B_ 2
#define T_ 2048
#define H_ 12
#define E_ 64
#define M_ 256
#define NBLK 32

typedef _Float16 f16;
typedef f16 f16x4 __attribute__((ext_vector_type(4)));
typedef f16 f16x8 __attribute__((ext_vector_type(8)));
typedef float f32x4 __attribute__((ext_vector_type(4)));

#define MFMA16(Av, Bv, Cv) __builtin_amdgcn_mfma_f32_16x16x32_f16(Av, Bv, Cv, 0, 0, 0)

constexpr float DN = 0.35355339059327373f;        // sqrt(temp)
constexpr float HALF_LOG_M = 2.7725887222397811f; // 0.5*ln(256)
constexpr float LN_CQ = 5.545177444479562f;       // ln(256): q' scale
constexpr float LN_CK = 2.772588722239781f;       // ln(16):  k' scale

__device__ __forceinline__ unsigned fkey(float f) {
  unsigned u = __float_as_uint(f);
  return (u & 0x80000000u) ? ~u : (u | 0x80000000u);
}
__device__ __forceinline__ float unfkey(unsigned k) {
  return (k & 0x80000000u) ? __uint_as_float(k & 0x7fffffffu) : __uint_as_float(~k);
}

// ---------------- workspace layout (bytes) ----------------
// 0         : skb     uint[24]                       (pad 256)
// 256       : projh   f16 [256][64]        32768 ->     33024
// 33024     : ksh     f16 [24][2048][64] 6291456 ->   6324480
// 6324480   : kd      f32 [24][2048]      196608 ->   6521088
// 6521088   : k_prime f16 [24][2048][256] 25165824 -> 31686912
// 31686912  : dots    f16 [24][2048][192] 18874368 -> 50561280
//   kvacc8 overlay f32 [8][24][68][256] 13369344 @ 37191936 (read before dots written)
// 50561280  : kvT     f16 [24][80][256]    983040 ->  51544320  (< proven 52.13 MB)
#define PSTRIDEF 417792  // 24*68*256 floats per partial

__global__ void init_ws(unsigned* __restrict__ skb, f16* __restrict__ projh,
                        const float* __restrict__ proj) {
  int i = blockIdx.x * blockDim.x + threadIdx.x;
  if (i < B_ * H_) skb[i] = 0u;
  if (i < M_ * E_) projh[i] = (f16)proj[i];
}

// prep_k: store ksh (DN-scaled f16) + kd (f32); GEMM k_dash; global max -> skb
__global__ __launch_bounds__(512) void prep_k(
    const float* __restrict__ key, const f16* __restrict__ projh,
    unsigned* __restrict__ skb, f16* __restrict__ ksh, float* __restrict__ kd) {
  __shared__ float red[8];
  const int blk = blockIdx.x;  // 24 bh x 8 chunks
  const int chunk = blk & 7, bh = blk >> 3;
  const int b = bh / H_, h = bh % H_;
  const int t = threadIdx.x;
  const int w = t >> 6, l = t & 63, l15 = l & 15, g4 = l >> 4;
  const int rblk = w & 3, cH = w >> 2, r0 = rblk * 16;
  float lmax = -3.0e38f;

  for (int ti = 0; ti < 4; ++ti) {
    const int t0 = chunk * 256 + ti * 64;
    const int trow = t0 + r0 + l15;
    f16x8 avk[2];
    float kdl = 0.f;
    const float* gk = key + (((size_t)b * T_ + trow) * H_ + h) * E_;
#pragma unroll
    for (int kk = 0; kk < 2; ++kk) {
      int e0 = kk * 32 + g4 * 8;
      float4 a = *(const float4*)(gk + e0);
      float4 bq = *(const float4*)(gk + e0 + 4);
      float x0 = a.x * DN, x1 = a.y * DN, x2 = a.z * DN, x3 = a.w * DN;
      float y0 = bq.x * DN, y1 = bq.y * DN, y2 = bq.z * DN, y3 = bq.w * DN;
      avk[kk] = (f16x8){(f16)x0, (f16)x1, (f16)x2, (f16)x3,
                        (f16)y0, (f16)y1, (f16)y2, (f16)y3};
      kdl += x0 * x0 + x1 * x1 + x2 * x2 + x3 * x3 + y0 * y0 + y1 * y1 + y2 * y2 + y3 * y3;
    }
    kdl *= 0.5f;
    kdl += __shfl_xor(kdl, 16);
    kdl += __shfl_xor(kdl, 32);
    if (cH == 0) {
      f16* ko = ksh + (size_t)(bh * T_ + trow) * E_;
      *(f16x8*)(ko + g4 * 8) = avk[0];
      *(f16x8*)(ko + 32 + g4 * 8) = avk[1];
      if (l < 16) kd[bh * T_ + trow] = kdl;
    }
    f32x4 acc[8];
#pragma unroll
    for (int ct = 0; ct < 8; ++ct) acc[ct] = (f32x4){0.f, 0.f, 0.f, 0.f};
#pragma unroll
    for (int kk = 0; kk < 2; ++kk)
#pragma unroll
      for (int ct = 0; ct < 8; ++ct) {
        int m = cH * 128 + ct * 16 + l15;
        f16x8 bv = *(const f16x8*)(projh + (size_t)m * E_ + kk * 32 + g4 * 8);
        acc[ct] = MFMA16(avk[kk], bv, acc[ct]);
      }
    float kd4[4];
#pragma unroll
    for (int r = 0; r < 4; ++r) kd4[r] = __shfl(kdl, (l & 48) + g4 * 4 + r);
#pragma unroll
    for (int ct = 0; ct < 8; ++ct)
#pragma unroll
      for (int r = 0; r < 4; ++r) lmax = fmaxf(lmax, acc[ct][r] - kd4[r]);
  }
#pragma unroll
  for (int off = 32; off; off >>= 1) lmax = fmaxf(lmax, __shfl_xor(lmax, off));
  if (l == 0) red[w] = lmax;
  __syncthreads();
  if (t == 0) {
    float mm = red[0];
#pragma unroll
    for (int ww = 1; ww < 8; ++ww) mm = fmaxf(mm, red[ww]);
    atomicMax(skb + bh, fkey(mm));
  }
}

// kpv: k_prime = 16*exp(k_shift - s_k) -> global f16 AND (via LDS transpose)
// kv partial GEMM for this chunk: kvacc8[chunk][bh][d][m] (+ones col d=64).
__global__ __launch_bounds__(512) void kpv_kernel(
    const float* __restrict__ value, const f16* __restrict__ ksh,
    const float* __restrict__ kd, const f16* __restrict__ projh,
    const unsigned* __restrict__ skb, f16* __restrict__ k_prime,
    float* __restrict__ kvacc8) {
  __shared__ f16 kpT[M_][72];
  __shared__ f16 vT[80][72];
  const int blk = blockIdx.x;  // 24 bh x 8 chunks
  const int chunk = blk & 7, bh = blk >> 3;
  const int b = bh / H_, h = bh % H_;
  const int t = threadIdx.x;
  const int w = t >> 6, l = t & 63, l15 = l & 15, g4 = l >> 4;
  const int rblk = w & 3, cH = w >> 2, r0 = rblk * 16;
  const float skv = unfkey(skb[bh]);

  for (int idx = t; idx < 16 * 72; idx += 512) {
    int rr = idx / 72, cc = idx % 72;
    vT[64 + rr][cc] = (rr == 0) ? (f16)1.0f : (f16)0.0f;
  }
  f32x4 acc[2][5];
#pragma unroll
  for (int q = 0; q < 2; ++q)
#pragma unroll
    for (int n2 = 0; n2 < 5; ++n2) acc[q][n2] = (f32x4){0.f, 0.f, 0.f, 0.f};

  for (int ti = 0; ti < 4; ++ti) {
    const int t0 = chunk * 256 + ti * 64;
    const int trow = t0 + r0 + l15;
    const f16* gk = ksh + (size_t)(bh * T_ + trow) * E_;
    f16x8 avk0 = *(const f16x8*)(gk + g4 * 8);
    f16x8 avk1 = *(const f16x8*)(gk + 32 + g4 * 8);
    f32x4 kacc[8];
#pragma unroll
    for (int ct = 0; ct < 8; ++ct) kacc[ct] = (f32x4){0.f, 0.f, 0.f, 0.f};
#pragma unroll
    for (int ct = 0; ct < 8; ++ct) {
      int m = cH * 128 + ct * 16 + l15;
      f16x8 bv0 = *(const f16x8*)(projh + (size_t)m * E_ + g4 * 8);
      f16x8 bv1 = *(const f16x8*)(projh + (size_t)m * E_ + 32 + g4 * 8);
      kacc[ct] = MFMA16(avk0, bv0, kacc[ct]);
      kacc[ct] = MFMA16(avk1, bv1, kacc[ct]);
    }
    float kd4[4];
#pragma unroll
    for (int r = 0; r < 4; ++r) kd4[r] = kd[bh * T_ + t0 + r0 + g4 * 4 + r];
    __syncthreads();  // prev ti GEMM reads done
    const int tloc = r0 + g4 * 4;
    const int uw = tloc >> 3, off = tloc & 7;
#pragma unroll
    for (int ct = 0; ct < 8; ++ct) {
      int m = cH * 128 + ct * 16 + l15;
      f16x4 pk;
#pragma unroll
      for (int r = 0; r < 4; ++r) {
        float kp = __expf(kacc[ct][r] - kd4[r] - skv + LN_CK);
        pk[r] = (f16)kp;
        k_prime[((size_t)bh * T_ + t0 + tloc + r) * M_ + m] = pk[r];
      }
      *(f16x4*)&kpT[m][(uw ^ ((m >> 1) & 7)) * 8 + off] = pk;
    }
    {
      int d = l, t8 = w;
      const float* gv = value + (((size_t)b * T_ + t0 + t8 * 8) * H_ + h) * E_ + d;
      f16x8 a;
#pragma unroll
      for (int r = 0; r < 8; ++r) a[r] = (f16)gv[(size_t)r * H_ * E_];
      *(f16x8*)&vT[d][(t8 ^ ((d >> 1) & 7)) * 8] = a;
    }
    __syncthreads();
#pragma unroll
    for (int kk = 0; kk < 2; ++kk) {
      int u = kk * 4 + g4;
      f16x8 afr[2];
#pragma unroll
      for (int q = 0; q < 2; ++q) {
        int m = (w * 2 + q) * 16 + l15;
        afr[q] = *(const f16x8*)&kpT[m][(u ^ ((m >> 1) & 7)) * 8];
      }
#pragma unroll
      for (int n2 = 0; n2 < 5; ++n2) {
        int d = n2 * 16 + l15;
        f16x8 bfr = *(const f16x8*)&vT[d][(u ^ ((d >> 1) & 7)) * 8];
#pragma unroll
        for (int q = 0; q < 2; ++q) acc[q][n2] = MFMA16(afr[q], bfr, acc[q][n2]);
      }
    }
  }
#pragma unroll
  for (int q = 0; q < 2; ++q)
#pragma unroll
    for (int n2 = 0; n2 < 5; ++n2) {
      int d = n2 * 16 + l15;
      if (d < 68) {
        int m0 = (w * 2 + q) * 16 + g4 * 4;
        float4 st = {acc[q][n2][0], acc[q][n2][1], acc[q][n2][2], acc[q][n2][3]};
        *(float4*)(kvacc8 + (size_t)chunk * PSTRIDEF + ((size_t)bh * 68 + d) * M_ + m0) = st;
      }
    }
}

// reduce 8 partials -> kvT f16 (x0.25; rows 68..79 zero)
__global__ __launch_bounds__(256) void kvred_kernel(
    const float* __restrict__ kvacc8, f16* __restrict__ kvT) {
  int idx = blockIdx.x * 256 + threadIdx.x;  // 480 blocks
  int m0 = (idx & 63) * 4;
  int rd = idx >> 6;
  int bh = rd / 80, d = rd - bh * 80;
  float4 s = {0.f, 0.f, 0.f, 0.f};
  if (d < 68) {
    const float* p = kvacc8 + ((size_t)bh * 68 + d) * M_ + m0;
#pragma unroll
    for (int c = 0; c < 8; ++c) {
      float4 u = *(const float4*)(p + (size_t)c * PSTRIDEF);
      s.x += u.x; s.y += u.y; s.z += u.z; s.w += u.w;
    }
  }
  f16x4 hv = {(f16)(0.25f * s.x), (f16)(0.25f * s.y),
              (f16)(0.25f * s.z), (f16)(0.25f * s.w)};
  *(f16x4*)(kvT + ((size_t)bh * 80 + d) * M_ + m0) = hv;
}

// dots_kernel: per (b,h, 32-row tile). q',dp,qkv,QK,stats; writes dots f16
// tile + low-rank term into out. Branch-free clamped windows.
__global__ __launch_bounds__(512) void dots_kernel(
    const float* __restrict__ query, const f16* __restrict__ ksh,
    const f16* __restrict__ projh, const f16* __restrict__ k_prime,
    const f16* __restrict__ kvT, const unsigned* __restrict__ skb,
    f16* __restrict__ dots, float* __restrict__ out) {
  __shared__ f16 qpL[32][296];  // 18944 B, row stride 592B (conflict-light)
  __shared__ float wmaxq[32][4], wmax[32][4], ps2[32][4], ds2[32][4];
  __shared__ float qdrow[32], qp1row[32], efac[32], psr[32];

  const int blk = blockIdx.x;
  const int rt = blk & 63;
  const int bh = blk >> 6;
  const int b = bh / H_, h = bh % H_;
  const int t0g = rt * 32;
  const int nb = rt >> 1;
  const int t = threadIdx.x;
  const int w = t >> 6, l = t & 63, l15 = l & 15, g4 = l >> 4;
  const int rb = w & 1, cq = w >> 1;
  const int r_w = rb * 16;
  const float s_k = unfkey(skb[bh]);

  int tkw[3];
  bool wvalid[3];
#pragma unroll
  for (int wi = 0; wi < 3; ++wi) {
    int rbk = nb - 1 + wi;
    wvalid[wi] = (rbk >= 0) && (rbk < NBLK);
    tkw[wi] = ((rbk < 0) ? 0 : (rbk > NBLK - 1 ? NBLK - 1 : rbk)) * 64;
  }

  // ---- q A-frags + q_diag ----
  f16x8 av_q[2];
  {
    float qdl = 0.f;
    const float* gq = query + (((size_t)b * T_ + t0g + r_w + l15) * H_ + h) * E_;
#pragma unroll
    for (int kk = 0; kk < 2; ++kk) {
      int e0 = kk * 32 + g4 * 8;
      float4 a = *(const float4*)(gq + e0);
      float4 c = *(const float4*)(gq + e0 + 4);
      float x0 = a.x * DN, x1 = a.y * DN, x2 = a.z * DN, x3 = a.w * DN;
      float y0 = c.x * DN, y1 = c.y * DN, y2 = c.z * DN, y3 = c.w * DN;
      av_q[kk] = (f16x8){(f16)x0, (f16)x1, (f16)x2, (f16)x3,
                         (f16)y0, (f16)y1, (f16)y2, (f16)y3};
      qdl += x0 * x0 + x1 * x1 + x2 * x2 + x3 * x3 + y0 * y0 + y1 * y1 + y2 * y2 + y3 * y3;
    }
    qdl *= 0.5f;
    qdl += __shfl_xor(qdl, 16);
    qdl += __shfl_xor(qdl, 32);
    if (cq == 0 && l < 16) qdrow[r_w + l15] = qdl;
  }

  // ---- q_dash GEMM (batched B loads) ----
  f32x4 qdacc[4];
#pragma unroll
  for (int ct = 0; ct < 4; ++ct) qdacc[ct] = (f32x4){0.f, 0.f, 0.f, 0.f};
  {
    f16x8 pb[8];
#pragma unroll
    for (int ct = 0; ct < 4; ++ct)
#pragma unroll
      for (int kk = 0; kk < 2; ++kk)
        pb[ct * 2 + kk] = *(const f16x8*)(projh + (size_t)(cq * 64 + ct * 16 + l15) * E_ + kk * 32 + g4 * 8);
#pragma unroll
    for (int ct = 0; ct < 4; ++ct) {
      qdacc[ct] = MFMA16(av_q[0], pb[ct * 2], qdacc[ct]);
      qdacc[ct] = MFMA16(av_q[1], pb[ct * 2 + 1], qdacc[ct]);
    }
  }
#pragma unroll
  for (int r = 0; r < 4; ++r) {
    float mx = fmaxf(fmaxf(qdacc[0][r], qdacc[1][r]), fmaxf(qdacc[2][r], qdacc[3][r]));
#pragma unroll
    for (int off = 1; off <= 8; off <<= 1) mx = fmaxf(mx, __shfl_xor(mx, off));
    if (l15 == 0) wmaxq[r_w + g4 * 4 + r][cq] = mx;
  }
  __syncthreads();  // B1

  {
    float sq4[4];
#pragma unroll
    for (int r = 0; r < 4; ++r) {
      int row = r_w + g4 * 4 + r;
      sq4[r] = fmaxf(fmaxf(wmaxq[row][0], wmaxq[row][1]), fmaxf(wmaxq[row][2], wmaxq[row][3]));
    }
#pragma unroll
    for (int ct = 0; ct < 4; ++ct) {
      int m = cq * 64 + ct * 16 + l15;
#pragma unroll
      for (int r = 0; r < 4; ++r)
        qpL[r_w + g4 * 4 + r][m] = (f16)__expf(qdacc[ct][r] - sq4[r] + LN_CQ);
    }
  }
  __syncthreads();  // B2

  // ---- QK GEMM (batched f16 B loads from ksh) ----
  f32x4 sacc[3];
#pragma unroll
  for (int a = 0; a < 3; ++a) sacc[a] = (f32x4){0.f, 0.f, 0.f, 0.f};
  {
    f16x8 kb[6];
#pragma unroll
    for (int wi = 0; wi < 3; ++wi)
#pragma unroll
      for (int kk = 0; kk < 2; ++kk)
        kb[wi * 2 + kk] = *(const f16x8*)(ksh + (size_t)(bh * T_ + tkw[wi] + cq * 16 + l15) * E_ + kk * 32 + g4 * 8);
#pragma unroll
    for (int wi = 0; wi < 3; ++wi) {
      sacc[wi] = MFMA16(av_q[0], kb[wi * 2], sacc[wi]);
      sacc[wi] = MFMA16(av_q[1], kb[wi * 2 + 1], sacc[wi]);
    }
  }

  // ---- dp + qkv GEMMs (per-kk batched loads, full unroll) ----
  f32x4 dacc[3], qkv[2];
#pragma unroll
  for (int a = 0; a < 3; ++a) dacc[a] = (f32x4){0.f, 0.f, 0.f, 0.f};
  qkv[0] = qkv[1] = (f32x4){0.f, 0.f, 0.f, 0.f};
#pragma unroll
  for (int kk = 0; kk < 8; ++kk) {
    f16x8 ap = *(const f16x8*)&qpL[r_w + l15][kk * 32 + g4 * 8];
    f16x8 bd0 = *(const f16x8*)(k_prime + (size_t)(bh * T_ + tkw[0] + cq * 16 + l15) * M_ + kk * 32 + g4 * 8);
    f16x8 bd1 = *(const f16x8*)(k_prime + (size_t)(bh * T_ + tkw[1] + cq * 16 + l15) * M_ + kk * 32 + g4 * 8);
    f16x8 bd2 = *(const f16x8*)(k_prime + (size_t)(bh * T_ + tkw[2] + cq * 16 + l15) * M_ + kk * 32 + g4 * 8);
    f16x8 bq0 = *(const f16x8*)(kvT + (size_t)(bh * 80 + cq * 16 + l15) * M_ + kk * 32 + g4 * 8);
    dacc[0] = MFMA16(ap, bd0, dacc[0]);
    dacc[1] = MFMA16(ap, bd1, dacc[1]);
    dacc[2] = MFMA16(ap, bd2, dacc[2]);
    qkv[0] = MFMA16(ap, bq0, qkv[0]);
    if (cq == 0) {
      f16x8 bq1 = *(const f16x8*)(kvT + (size_t)(bh * 80 + 64 + l15) * M_ + kk * 32 + g4 * 8);
      qkv[1] = MFMA16(ap, bq1, qkv[1]);
    }
  }

  // ---- QK row max + qp1 ----
#pragma unroll
  for (int r = 0; r < 4; ++r) {
    float mx = -3.0e38f;
#pragma unroll
    for (int wi = 0; wi < 3; ++wi)
      if (wvalid[wi]) mx = fmaxf(mx, sacc[wi][r]);
#pragma unroll
    for (int off = 1; off <= 8; off <<= 1) mx = fmaxf(mx, __shfl_xor(mx, off));
    if (l15 == 0) wmax[r_w + g4 * 4 + r][cq] = mx;
  }
  if (cq == 0 && l15 == 0) {
#pragma unroll
    for (int r = 0; r < 4; ++r) qp1row[r_w + g4 * 4 + r] = 4.0f * qkv[1][r];
  }
  __syncthreads();  // B3

  // ---- exp + row sums ----
  {
    float m4[4];
#pragma unroll
    for (int r = 0; r < 4; ++r) {
      int row = r_w + g4 * 4 + r;
      m4[r] = fmaxf(fmaxf(wmax[row][0], wmax[row][1]), fmaxf(wmax[row][2], wmax[row][3]));
    }
    float psl[4] = {0.f, 0.f, 0.f, 0.f}, dsl[4] = {0.f, 0.f, 0.f, 0.f};
#pragma unroll
    for (int wi = 0; wi < 3; ++wi) {
      if (wvalid[wi]) {
#pragma unroll
        for (int r = 0; r < 4; ++r) {
          sacc[wi][r] = __expf(sacc[wi][r] - m4[r]);
          psl[r] += sacc[wi][r];
          dsl[r] += dacc[wi][r];
        }
      } else {
#pragma unroll
        for (int r = 0; r < 4; ++r) { sacc[wi][r] = 0.f; dacc[wi][r] = 0.f; }
      }
    }
#pragma unroll
    for (int r = 0; r < 4; ++r) {
#pragma unroll
      for (int off = 1; off <= 8; off <<= 1) {
        psl[r] += __shfl_xor(psl[r], off);
        dsl[r] += __shfl_xor(dsl[r], off);
      }
      if (l15 == 0) {
        int row = r_w + g4 * 4 + r;
        ps2[row][cq] = psl[r];
        ds2[row][cq] = dsl[r];
      }
    }
  }
  __syncthreads();  // B4

  if (t < 32) {
    float mrow = fmaxf(fmaxf(wmax[t][0], wmax[t][1]), fmaxf(wmax[t][2], wmax[t][3]));
    float lse = mrow + __logf(ps2[t][0] + ps2[t][1] + ps2[t][2] + ps2[t][3]);
    float dsum = ds2[t][0] + ds2[t][1] + ds2[t][2] + ds2[t][3];
    float sqrow = fmaxf(fmaxf(wmaxq[t][0], wmaxq[t][1]), fmaxf(wmaxq[t][2], wmaxq[t][3]));
    float plsC = sqrow - qdrow[t] - HALF_LOG_M + s_k - HALF_LOG_M - LN_CQ - LN_CK;
    float lr = __logf(fmaxf(qp1row[t] - dsum, 1e-24f)) + plsC;
    float mm = fmaxf(lse, lr);
    float ln = mm + __logf(__expf(lse - mm) + __expf(lr - mm));
    efac[t] = __expf(mrow - ln);
    psr[t] = __expf(plsC - ln);
  }
  __syncthreads();  // B5

  float ef4[4], ps4[4];
#pragma unroll
  for (int r = 0; r < 4; ++r) {
    int row = r_w + g4 * 4 + r;
    ef4[r] = efac[row];
    ps4[r] = psr[row];
  }
  f16* drow = dots + (size_t)(bh * T_ + t0g) * 192;
#pragma unroll
  for (int wi = 0; wi < 3; ++wi) {
    int c = wi * 64 + cq * 16 + l15;
#pragma unroll
    for (int r = 0; r < 4; ++r)
      drow[(size_t)(r_w + g4 * 4 + r) * 192 + c] =
          (f16)(sacc[wi][r] * ef4[r] - dacc[wi][r] * ps4[r]);
  }
  {
    int d = cq * 16 + l15;
#pragma unroll
    for (int r = 0; r < 4; ++r) {
      int row = r_w + g4 * 4 + r;
      out[(((size_t)b * T_ + t0g + row) * H_ + h) * E_ + d] = 4.0f * qkv[0][r] * ps4[r];
    }
  }
}

// pv_kernel: out += dots . V^T  (batched A-frag loads)
__global__ __launch_bounds__(512) void pv_kernel(
    const float* __restrict__ value, const f16* __restrict__ dots,
    float* __restrict__ out) {
  __shared__ f16 vTh[64][200];  // 25600 B

  const int blk = blockIdx.x;
  const int nb = blk & (NBLK - 1);
  const int bh = blk >> 5;
  const int b = bh / H_, h = bh % H_;
  const int t0g = nb * 64;
  const int t = threadIdx.x;
  const int w = t >> 6, l = t & 63, l15 = l & 15, g4 = l >> 4;
  const int rblk = w & 3, cH = w >> 2, r0 = rblk * 16;

  int tkw[3];
#pragma unroll
  for (int wi = 0; wi < 3; ++wi) {
    int rbk = nb - 1 + wi;
    tkw[wi] = ((rbk < 0) ? 0 : (rbk > NBLK - 1 ? NBLK - 1 : rbk)) * 64;
  }

  // stage V^T (3 windows, clamped; invalid windows have dots==0)
  {
    int d = l;
#pragma unroll
    for (int it = 0; it < 3; ++it) {
      int tg = it * 8 + w;  // 0..23
      int wi = tg >> 3, j = (tg & 7) * 8;
      const float* gv = value + (((size_t)b * T_ + tkw[wi] + j) * H_ + h) * E_ + d;
      f16x8 a;
#pragma unroll
      for (int r = 0; r < 8; ++r) a[r] = (f16)gv[(size_t)r * H_ * E_];
      *(f16x8*)&vTh[d][(tg ^ (d & 7)) * 8] = a;
    }
  }
  // batched A-frag loads (in flight across barrier)
  f16x8 af[6];
  const f16* drow = dots + (size_t)(bh * T_ + t0g + r0 + l15) * 192;
#pragma unroll
  for (int kk = 0; kk < 6; ++kk) af[kk] = *(const f16x8*)(drow + kk * 32 + g4 * 8);
  __syncthreads();

  f32x4 oacc[2];
  oacc[0] = oacc[1] = (f32x4){0.f, 0.f, 0.f, 0.f};
#pragma unroll
  for (int kk = 0; kk < 6; ++kk) {
    int u = kk * 4 + g4;
#pragma unroll
    for (int q2 = 0; q2 < 2; ++q2) {
      int d = cH * 32 + q2 * 16 + l15;
      f16x8 bv = *(const f16x8*)&vTh[d][(u ^ (d & 7)) * 8];
      oacc[q2] = MFMA16(af[kk], bv, oacc[q2]);
    }
  }
#pragma unroll
  for (int q2 = 0; q2 < 2; ++q2) {
    int d = cH * 32 + q2 * 16 + l15;
#pragma unroll
    for (int r = 0; r < 4; ++r) {
      int row = r0 + g4 * 4 + r;
      size_t oidx = (((size_t)b * T_ + t0g + row) * H_ + h) * E_ + d;
      out[oidx] += oacc[q2][r];
    }
  }
}

extern "C" void kernel_launch(void* const* d_in, const int* in_sizes, int n_in,
                              void* d_out, int out_size, void* d_ws, size_t ws_size,
                              hipStream_t stream) {
  const float* query = (const float*)d_in[0];
  const float* key   = (const float*)d_in[1];
  const float* value = (const float*)d_in[2];
  const float* proj  = (const float*)d_in[3];
  float* out = (float*)d_out;

  char* ws = (char*)d_ws;
  unsigned* skb = (unsigned*)ws;
  f16* projh   = (f16*)(ws + 256);
  f16* ksh     = (f16*)(ws + 33024);
  float* kd    = (float*)(ws + 6324480);
  f16* k_prime = (f16*)(ws + 6521088);
  f16* dots    = (f16*)(ws + 31686912);
  float* kvacc8 = (float*)(ws + 37191936);  // overlay inside dots region
  f16* kvT     = (f16*)(ws + 50561280);

  init_ws<<<64, 256, 0, stream>>>(skb, projh, proj);
  prep_k<<<B_ * H_ * 8, 512, 0, stream>>>(key, projh, skb, ksh, kd);
  kpv_kernel<<<B_ * H_ * 8, 512, 0, stream>>>(value, ksh, kd, projh, skb, k_prime, kvacc8);
  kvred_kernel<<<480, 256, 0, stream>>>(kvacc8, kvT);
  dots_kernel<<<B_ * H_ * 64, 512, 0, stream>>>(query, ksh, projh, k_prime, kvT, skb, dots, out);
  pv_kernel<<<B_ * H_ * NBLK, 512, 0, stream>>>(value, dots, out);
}

// Round 6
// 130.948 us; speedup vs baseline: 1.8365x; 1.0684x over previous
//
#include <hip/hip_runtime.h>

#define B_ 2
#define T_ 2048
#define H_ 12
#define E_ 64
#define M_ 256
#define NBLK 32

typedef _Float16 f16;
typedef f16 f16x4 __attribute__((ext_vector_type(4)));
typedef f16 f16x8 __attribute__((ext_vector_type(8)));
typedef float f32x4 __attribute__((ext_vector_type(4)));

#define MFMA16(Av, Bv, Cv) __builtin_amdgcn_mfma_f32_16x16x32_f16(Av, Bv, Cv, 0, 0, 0)

constexpr float DN = 0.35355339059327373f;        // sqrt(temp)
constexpr float HALF_LOG_M = 2.7725887222397811f; // 0.5*ln(256)
constexpr float LN_CQ = 5.545177444479562f;       // ln(256): q' scale
constexpr float LN_CK = 2.772588722239781f;       // ln(16):  k' scale

__device__ __forceinline__ unsigned fkey(float f) {
  unsigned u = __float_as_uint(f);
  return (u & 0x80000000u) ? ~u : (u | 0x80000000u);
}
__device__ __forceinline__ float unfkey(unsigned k) {
  return (k & 0x80000000u) ? __uint_as_float(k & 0x7fffffffu) : __uint_as_float(~k);
}

// ---------------- workspace layout (bytes) ----------------
// 0         : skb     uint[24]                        (pad 256)
// 256       : projh   f16 [256][64]         32768 ->     33024
// 33024     : ksh     f16 [24][2048][64]  6291456 ->   6324480
// 6324480   : kd      f32 [24][2048]       196608 ->   6521088
// 6521088   : k_prime f16 [24][2048][256] 25165824 -> 31686912
// 31686912  : vTT     f16 [24][64][2048]  6291456 ->  37978368
// 37978368  : kvacc8  f32 [8][24][65][256] 12779520 -> 50757888
// 50757888  : kvT     f16 [24][80][256]     983040 ->  51740928  (< proven 52.13 MB)
#define PSTRIDEF 399360  // 24*65*256 floats per partial

__global__ void init_ws(unsigned* __restrict__ skb, f16* __restrict__ projh,
                        const float* __restrict__ proj) {
  int i = blockIdx.x * blockDim.x + threadIdx.x;
  if (i < B_ * H_) skb[i] = 0u;
  if (i < M_ * E_) projh[i] = (f16)proj[i];
}

// prep_k: store ksh (DN-scaled f16) + kd (f32); GEMM k_dash; global max -> skb
__global__ __launch_bounds__(512) void prep_k(
    const float* __restrict__ key, const f16* __restrict__ projh,
    unsigned* __restrict__ skb, f16* __restrict__ ksh, float* __restrict__ kd) {
  __shared__ float red[8];
  const int blk = blockIdx.x;  // 24 bh x 8 chunks
  const int chunk = blk & 7, bh = blk >> 3;
  const int b = bh / H_, h = bh % H_;
  const int t = threadIdx.x;
  const int w = t >> 6, l = t & 63, l15 = l & 15, g4 = l >> 4;
  const int rblk = w & 3, cH = w >> 2, r0 = rblk * 16;
  float lmax = -3.0e38f;

  for (int ti = 0; ti < 4; ++ti) {
    const int t0 = chunk * 256 + ti * 64;
    const int trow = t0 + r0 + l15;
    f16x8 avk[2];
    float kdl = 0.f;
    const float* gk = key + (((size_t)b * T_ + trow) * H_ + h) * E_;
#pragma unroll
    for (int kk = 0; kk < 2; ++kk) {
      int e0 = kk * 32 + g4 * 8;
      float4 a = *(const float4*)(gk + e0);
      float4 bq = *(const float4*)(gk + e0 + 4);
      float x0 = a.x * DN, x1 = a.y * DN, x2 = a.z * DN, x3 = a.w * DN;
      float y0 = bq.x * DN, y1 = bq.y * DN, y2 = bq.z * DN, y3 = bq.w * DN;
      avk[kk] = (f16x8){(f16)x0, (f16)x1, (f16)x2, (f16)x3,
                        (f16)y0, (f16)y1, (f16)y2, (f16)y3};
      kdl += x0 * x0 + x1 * x1 + x2 * x2 + x3 * x3 + y0 * y0 + y1 * y1 + y2 * y2 + y3 * y3;
    }
    kdl *= 0.5f;
    kdl += __shfl_xor(kdl, 16);
    kdl += __shfl_xor(kdl, 32);
    if (cH == 0) {
      f16* ko = ksh + (size_t)(bh * T_ + trow) * E_;
      *(f16x8*)(ko + g4 * 8) = avk[0];
      *(f16x8*)(ko + 32 + g4 * 8) = avk[1];
      if (l < 16) kd[bh * T_ + trow] = kdl;
    }
    f32x4 acc[8];
#pragma unroll
    for (int ct = 0; ct < 8; ++ct) acc[ct] = (f32x4){0.f, 0.f, 0.f, 0.f};
#pragma unroll
    for (int kk = 0; kk < 2; ++kk)
#pragma unroll
      for (int ct = 0; ct < 8; ++ct) {
        int m = cH * 128 + ct * 16 + l15;
        f16x8 bv = *(const f16x8*)(projh + (size_t)m * E_ + kk * 32 + g4 * 8);
        acc[ct] = MFMA16(avk[kk], bv, acc[ct]);
      }
    float kd4[4];
#pragma unroll
    for (int r = 0; r < 4; ++r) kd4[r] = __shfl(kdl, (l & 48) + g4 * 4 + r);
#pragma unroll
    for (int ct = 0; ct < 8; ++ct)
#pragma unroll
      for (int r = 0; r < 4; ++r) lmax = fmaxf(lmax, acc[ct][r] - kd4[r]);
  }
#pragma unroll
  for (int off = 32; off; off >>= 1) lmax = fmaxf(lmax, __shfl_xor(lmax, off));
  if (l == 0) red[w] = lmax;
  __syncthreads();
  if (t == 0) {
    float mm = red[0];
#pragma unroll
    for (int ww = 1; ww < 8; ++ww) mm = fmaxf(mm, red[ww]);
    atomicMax(skb + bh, fkey(mm));
  }
}

// kpv: k_prime = 16*exp(k_shift - s_k) -> global f16; kv partial GEMM chunk;
// ALSO writes the transposed V (f16) to vTT[bh][d][t] for the fused PV.
__global__ __launch_bounds__(512) void kpv_kernel(
    const float* __restrict__ value, const f16* __restrict__ ksh,
    const float* __restrict__ kd, const f16* __restrict__ projh,
    const unsigned* __restrict__ skb, f16* __restrict__ k_prime,
    float* __restrict__ kvacc8, f16* __restrict__ vTT) {
  __shared__ f16 kpT[M_][72];
  __shared__ f16 vT[80][72];
  const int blk = blockIdx.x;  // 24 bh x 8 chunks
  const int chunk = blk & 7, bh = blk >> 3;
  const int b = bh / H_, h = bh % H_;
  const int t = threadIdx.x;
  const int w = t >> 6, l = t & 63, l15 = l & 15, g4 = l >> 4;
  const int rblk = w & 3, cH = w >> 2, r0 = rblk * 16;
  const float skv = unfkey(skb[bh]);

  for (int idx = t; idx < 16 * 72; idx += 512) {
    int rr = idx / 72, cc = idx % 72;
    vT[64 + rr][cc] = (rr == 0) ? (f16)1.0f : (f16)0.0f;
  }
  f32x4 acc[2][5];
#pragma unroll
  for (int q = 0; q < 2; ++q)
#pragma unroll
    for (int n2 = 0; n2 < 5; ++n2) acc[q][n2] = (f32x4){0.f, 0.f, 0.f, 0.f};

  for (int ti = 0; ti < 4; ++ti) {
    const int t0 = chunk * 256 + ti * 64;
    const int trow = t0 + r0 + l15;
    const f16* gk = ksh + (size_t)(bh * T_ + trow) * E_;
    f16x8 avk0 = *(const f16x8*)(gk + g4 * 8);
    f16x8 avk1 = *(const f16x8*)(gk + 32 + g4 * 8);
    f32x4 kacc[8];
#pragma unroll
    for (int ct = 0; ct < 8; ++ct) kacc[ct] = (f32x4){0.f, 0.f, 0.f, 0.f};
#pragma unroll
    for (int ct = 0; ct < 8; ++ct) {
      int m = cH * 128 + ct * 16 + l15;
      f16x8 bv0 = *(const f16x8*)(projh + (size_t)m * E_ + g4 * 8);
      f16x8 bv1 = *(const f16x8*)(projh + (size_t)m * E_ + 32 + g4 * 8);
      kacc[ct] = MFMA16(avk0, bv0, kacc[ct]);
      kacc[ct] = MFMA16(avk1, bv1, kacc[ct]);
    }
    float kd4[4];
#pragma unroll
    for (int r = 0; r < 4; ++r) kd4[r] = kd[bh * T_ + t0 + r0 + g4 * 4 + r];
    __syncthreads();  // prev ti GEMM reads done
    const int tloc = r0 + g4 * 4;
    const int uw = tloc >> 3, off = tloc & 7;
#pragma unroll
    for (int ct = 0; ct < 8; ++ct) {
      int m = cH * 128 + ct * 16 + l15;
      f16x4 pk;
#pragma unroll
      for (int r = 0; r < 4; ++r) {
        float kp = __expf(kacc[ct][r] - kd4[r] - skv + LN_CK);
        pk[r] = (f16)kp;
        k_prime[((size_t)bh * T_ + t0 + tloc + r) * M_ + m] = pk[r];
      }
      *(f16x4*)&kpT[m][(uw ^ ((m >> 1) & 7)) * 8 + off] = pk;
    }
    {
      int d = l, t8 = w;
      const float* gv = value + (((size_t)b * T_ + t0 + t8 * 8) * H_ + h) * E_ + d;
      f16x8 a;
#pragma unroll
      for (int r = 0; r < 8; ++r) a[r] = (f16)gv[(size_t)r * H_ * E_];
      *(f16x8*)&vT[d][(t8 ^ ((d >> 1) & 7)) * 8] = a;
    }
    __syncthreads();
    // write transposed V chunk to vTT (linear [d][t])
    {
      int d2 = t >> 3, t8 = t & 7;
      f16x8 vv = *(const f16x8*)&vT[d2][(t8 ^ ((d2 >> 1) & 7)) * 8];
      *(f16x8*)(vTT + ((size_t)bh * 64 + d2) * T_ + t0 + t8 * 8) = vv;
    }
#pragma unroll
    for (int kk = 0; kk < 2; ++kk) {
      int u = kk * 4 + g4;
      f16x8 afr[2];
#pragma unroll
      for (int q = 0; q < 2; ++q) {
        int m = (w * 2 + q) * 16 + l15;
        afr[q] = *(const f16x8*)&kpT[m][(u ^ ((m >> 1) & 7)) * 8];
      }
#pragma unroll
      for (int n2 = 0; n2 < 5; ++n2) {
        int d = n2 * 16 + l15;
        f16x8 bfr = *(const f16x8*)&vT[d][(u ^ ((d >> 1) & 7)) * 8];
#pragma unroll
        for (int q = 0; q < 2; ++q) acc[q][n2] = MFMA16(afr[q], bfr, acc[q][n2]);
      }
    }
  }
#pragma unroll
  for (int q = 0; q < 2; ++q)
#pragma unroll
    for (int n2 = 0; n2 < 5; ++n2) {
      int d = n2 * 16 + l15;
      if (d < 65) {
        int m0 = (w * 2 + q) * 16 + g4 * 4;
        float4 st = {acc[q][n2][0], acc[q][n2][1], acc[q][n2][2], acc[q][n2][3]};
        *(float4*)(kvacc8 + (size_t)chunk * PSTRIDEF + ((size_t)bh * 65 + d) * M_ + m0) = st;
      }
    }
}

// reduce 8 partials -> kvT f16 (x0.25; rows 65..79 zero)
__global__ __launch_bounds__(256) void kvred_kernel(
    const float* __restrict__ kvacc8, f16* __restrict__ kvT) {
  int idx = blockIdx.x * 256 + threadIdx.x;  // 480 blocks
  int m0 = (idx & 63) * 4;
  int rd = idx >> 6;
  int bh = rd / 80, d = rd - bh * 80;
  float4 s = {0.f, 0.f, 0.f, 0.f};
  if (d < 65) {
    const float* p = kvacc8 + ((size_t)bh * 65 + d) * M_ + m0;
#pragma unroll
    for (int c = 0; c < 8; ++c) {
      float4 u = *(const float4*)(p + (size_t)c * PSTRIDEF);
      s.x += u.x; s.y += u.y; s.z += u.z; s.w += u.w;
    }
  }
  f16x4 hv = {(f16)(0.25f * s.x), (f16)(0.25f * s.y),
              (f16)(0.25f * s.z), (f16)(0.25f * s.w)};
  *(f16x4*)(kvT + ((size_t)bh * 80 + d) * M_ + m0) = hv;
}

// main_fused: per (b,h, 32-row tile). q',dp,qkv,QK,stats,dots(LDS),PV,out.
// XCD chunk-swizzled grid. Depth-2 pipelined dp loads. PV B-frags from vTT.
__global__ __launch_bounds__(512) void main_fused(
    const float* __restrict__ query, const f16* __restrict__ ksh,
    const f16* __restrict__ projh, const f16* __restrict__ k_prime,
    const f16* __restrict__ kvT, const f16* __restrict__ vTT,
    const unsigned* __restrict__ skb, float* __restrict__ out) {
  __shared__ f16 qpL[32][296];  // q' tile, later dots tile (18944 B)
  __shared__ float wmaxq[32][4], wmax[32][4], ps2[32][4], ds2[32][4];
  __shared__ float qdrow[32], qp1row[32], efac[32], psr[32];

  // XCD-aware swizzle: chunks of 16 consecutive logical tiles per XCD.
  // grid=1536=12*128; bijective within each 128-block.
  const int D = blockIdx.x;
  const int L = (D & ~127) + (D & 7) * 16 + ((D & 127) >> 3);
  const int rt = L & 63;
  const int bh = L >> 6;
  const int b = bh / H_, h = bh % H_;
  const int t0g = rt * 32;
  const int nb = rt >> 1;
  const int t = threadIdx.x;
  const int w = t >> 6, l = t & 63, l15 = l & 15, g4 = l >> 4;
  const int rb = w & 1, cq = w >> 1;
  const int r_w = rb * 16;
  const float s_k = unfkey(skb[bh]);

  int tkw[3];
  bool wvalid[3];
#pragma unroll
  for (int wi = 0; wi < 3; ++wi) {
    int rbk = nb - 1 + wi;
    wvalid[wi] = (rbk >= 0) && (rbk < NBLK);
    tkw[wi] = ((rbk < 0) ? 0 : (rbk > NBLK - 1 ? NBLK - 1 : rbk)) * 64;
  }

  // ---- q A-frags + q_diag ----
  f16x8 av_q[2];
  {
    float qdl = 0.f;
    const float* gq = query + (((size_t)b * T_ + t0g + r_w + l15) * H_ + h) * E_;
#pragma unroll
    for (int kk = 0; kk < 2; ++kk) {
      int e0 = kk * 32 + g4 * 8;
      float4 a = *(const float4*)(gq + e0);
      float4 c = *(const float4*)(gq + e0 + 4);
      float x0 = a.x * DN, x1 = a.y * DN, x2 = a.z * DN, x3 = a.w * DN;
      float y0 = c.x * DN, y1 = c.y * DN, y2 = c.z * DN, y3 = c.w * DN;
      av_q[kk] = (f16x8){(f16)x0, (f16)x1, (f16)x2, (f16)x3,
                         (f16)y0, (f16)y1, (f16)y2, (f16)y3};
      qdl += x0 * x0 + x1 * x1 + x2 * x2 + x3 * x3 + y0 * y0 + y1 * y1 + y2 * y2 + y3 * y3;
    }
    qdl *= 0.5f;
    qdl += __shfl_xor(qdl, 16);
    qdl += __shfl_xor(qdl, 32);
    if (cq == 0 && l < 16) qdrow[r_w + l15] = qdl;
  }

  // ---- QK B-frag loads issued early (independent of barriers) ----
  f16x8 kb[6];
#pragma unroll
  for (int wi = 0; wi < 3; ++wi)
#pragma unroll
    for (int kk = 0; kk < 2; ++kk)
      kb[wi * 2 + kk] = *(const f16x8*)(ksh + (size_t)(bh * T_ + tkw[wi] + cq * 16 + l15) * E_ + kk * 32 + g4 * 8);

  // ---- q_dash GEMM (batched B loads) ----
  f32x4 qdacc[4];
#pragma unroll
  for (int ct = 0; ct < 4; ++ct) qdacc[ct] = (f32x4){0.f, 0.f, 0.f, 0.f};
  {
    f16x8 pb[8];
#pragma unroll
    for (int ct = 0; ct < 4; ++ct)
#pragma unroll
      for (int kk = 0; kk < 2; ++kk)
        pb[ct * 2 + kk] = *(const f16x8*)(projh + (size_t)(cq * 64 + ct * 16 + l15) * E_ + kk * 32 + g4 * 8);
#pragma unroll
    for (int ct = 0; ct < 4; ++ct) {
      qdacc[ct] = MFMA16(av_q[0], pb[ct * 2], qdacc[ct]);
      qdacc[ct] = MFMA16(av_q[1], pb[ct * 2 + 1], qdacc[ct]);
    }
  }
#pragma unroll
  for (int r = 0; r < 4; ++r) {
    float mx = fmaxf(fmaxf(qdacc[0][r], qdacc[1][r]), fmaxf(qdacc[2][r], qdacc[3][r]));
#pragma unroll
    for (int off = 1; off <= 8; off <<= 1) mx = fmaxf(mx, __shfl_xor(mx, off));
    if (l15 == 0) wmaxq[r_w + g4 * 4 + r][cq] = mx;
  }
  __syncthreads();  // B1

  // ---- QK GEMM (kb arrived during qdash/B1) ----
  f32x4 sacc[3];
#pragma unroll
  for (int a = 0; a < 3; ++a) sacc[a] = (f32x4){0.f, 0.f, 0.f, 0.f};
#pragma unroll
  for (int wi = 0; wi < 3; ++wi) {
    sacc[wi] = MFMA16(av_q[0], kb[wi * 2], sacc[wi]);
    sacc[wi] = MFMA16(av_q[1], kb[wi * 2 + 1], sacc[wi]);
  }

  // ---- q' = exp(qdash - s_q + LN_CQ) -> qpL ----
  {
    float sq4[4];
#pragma unroll
    for (int r = 0; r < 4; ++r) {
      int row = r_w + g4 * 4 + r;
      sq4[r] = fmaxf(fmaxf(wmaxq[row][0], wmaxq[row][1]), fmaxf(wmaxq[row][2], wmaxq[row][3]));
    }
#pragma unroll
    for (int ct = 0; ct < 4; ++ct) {
      int m = cq * 64 + ct * 16 + l15;
#pragma unroll
      for (int r = 0; r < 4; ++r)
        qpL[r_w + g4 * 4 + r][m] = (f16)__expf(qdacc[ct][r] - sq4[r] + LN_CQ);
    }
  }

  // ---- prefetch dp/qkv B-frags for kk=0 (in flight across B2) ----
  const f16* kpb0 = k_prime + (size_t)(bh * T_ + tkw[0] + cq * 16 + l15) * M_ + g4 * 8;
  const f16* kpb1 = k_prime + (size_t)(bh * T_ + tkw[1] + cq * 16 + l15) * M_ + g4 * 8;
  const f16* kpb2 = k_prime + (size_t)(bh * T_ + tkw[2] + cq * 16 + l15) * M_ + g4 * 8;
  const f16* kvb0 = kvT + (size_t)(bh * 80 + cq * 16 + l15) * M_ + g4 * 8;
  const f16* kvb1 = kvT + (size_t)(bh * 80 + 64 + l15) * M_ + g4 * 8;
  f16x8 bd0[2], bd1[2], bd2[2], bq0[2], bq1[2];
  bd0[0] = *(const f16x8*)(kpb0);
  bd1[0] = *(const f16x8*)(kpb1);
  bd2[0] = *(const f16x8*)(kpb2);
  bq0[0] = *(const f16x8*)(kvb0);
  if (cq == 0) bq1[0] = *(const f16x8*)(kvb1);
  __syncthreads();  // B2

  // ---- dp + qkv GEMMs, depth-2 pipeline ----
  f32x4 dacc[3], qkv[2];
#pragma unroll
  for (int a = 0; a < 3; ++a) dacc[a] = (f32x4){0.f, 0.f, 0.f, 0.f};
  qkv[0] = qkv[1] = (f32x4){0.f, 0.f, 0.f, 0.f};
#pragma unroll
  for (int kk = 0; kk < 8; ++kk) {
    const int cur = kk & 1, nxt = cur ^ 1;
    if (kk < 7) {
      const int o = (kk + 1) * 32;
      bd0[nxt] = *(const f16x8*)(kpb0 + o);
      bd1[nxt] = *(const f16x8*)(kpb1 + o);
      bd2[nxt] = *(const f16x8*)(kpb2 + o);
      bq0[nxt] = *(const f16x8*)(kvb0 + o);
      if (cq == 0) bq1[nxt] = *(const f16x8*)(kvb1 + o);
    }
    f16x8 ap = *(const f16x8*)&qpL[r_w + l15][kk * 32 + g4 * 8];
    dacc[0] = MFMA16(ap, bd0[cur], dacc[0]);
    dacc[1] = MFMA16(ap, bd1[cur], dacc[1]);
    dacc[2] = MFMA16(ap, bd2[cur], dacc[2]);
    qkv[0] = MFMA16(ap, bq0[cur], qkv[0]);
    if (cq == 0) qkv[1] = MFMA16(ap, bq1[cur], qkv[1]);
  }

  // ---- QK row max + qp1 ----
#pragma unroll
  for (int r = 0; r < 4; ++r) {
    float mx = -3.0e38f;
#pragma unroll
    for (int wi = 0; wi < 3; ++wi)
      if (wvalid[wi]) mx = fmaxf(mx, sacc[wi][r]);
#pragma unroll
    for (int off = 1; off <= 8; off <<= 1) mx = fmaxf(mx, __shfl_xor(mx, off));
    if (l15 == 0) wmax[r_w + g4 * 4 + r][cq] = mx;
  }
  if (cq == 0 && l15 == 0) {
#pragma unroll
    for (int r = 0; r < 4; ++r) qp1row[r_w + g4 * 4 + r] = 4.0f * qkv[1][r];
  }
  __syncthreads();  // B3

  // ---- exp + row sums ----
  {
    float m4[4];
#pragma unroll
    for (int r = 0; r < 4; ++r) {
      int row = r_w + g4 * 4 + r;
      m4[r] = fmaxf(fmaxf(wmax[row][0], wmax[row][1]), fmaxf(wmax[row][2], wmax[row][3]));
    }
    float psl[4] = {0.f, 0.f, 0.f, 0.f}, dsl[4] = {0.f, 0.f, 0.f, 0.f};
#pragma unroll
    for (int wi = 0; wi < 3; ++wi) {
      if (wvalid[wi]) {
#pragma unroll
        for (int r = 0; r < 4; ++r) {
          sacc[wi][r] = __expf(sacc[wi][r] - m4[r]);
          psl[r] += sacc[wi][r];
          dsl[r] += dacc[wi][r];
        }
      } else {
#pragma unroll
        for (int r = 0; r < 4; ++r) { sacc[wi][r] = 0.f; dacc[wi][r] = 0.f; }
      }
    }
#pragma unroll
    for (int r = 0; r < 4; ++r) {
#pragma unroll
      for (int off = 1; off <= 8; off <<= 1) {
        psl[r] += __shfl_xor(psl[r], off);
        dsl[r] += __shfl_xor(dsl[r], off);
      }
      if (l15 == 0) {
        int row = r_w + g4 * 4 + r;
        ps2[row][cq] = psl[r];
        ds2[row][cq] = dsl[r];
      }
    }
  }
  __syncthreads();  // B4

  if (t < 32) {
    float mrow = fmaxf(fmaxf(wmax[t][0], wmax[t][1]), fmaxf(wmax[t][2], wmax[t][3]));
    float lse = mrow + __logf(ps2[t][0] + ps2[t][1] + ps2[t][2] + ps2[t][3]);
    float dsum = ds2[t][0] + ds2[t][1] + ds2[t][2] + ds2[t][3];
    float sqrow = fmaxf(fmaxf(wmaxq[t][0], wmaxq[t][1]), fmaxf(wmaxq[t][2], wmaxq[t][3]));
    float plsC = sqrow - qdrow[t] - HALF_LOG_M + s_k - HALF_LOG_M - LN_CQ - LN_CK;
    float lr = __logf(fmaxf(qp1row[t] - dsum, 1e-24f)) + plsC;
    float mm = fmaxf(lse, lr);
    float ln = mm + __logf(__expf(lse - mm) + __expf(lr - mm));
    efac[t] = __expf(mrow - ln);
    psr[t] = __expf(plsC - ln);
  }

  // ---- prefetch PV B-frags from vTT (f16, L2-hot; clamped windows) ----
  f16x8 bvv[6];
#pragma unroll
  for (int kk = 0; kk < 6; ++kk)
    bvv[kk] = *(const f16x8*)(vTT + ((size_t)bh * 64 + cq * 16 + l15) * T_
                              + tkw[kk >> 1] + (kk & 1) * 32 + g4 * 8);
  __syncthreads();  // B5

  // ---- dots tile into qpL (reuse; q' dead) ----
  float ef4[4], ps4[4];
#pragma unroll
  for (int r = 0; r < 4; ++r) {
    int row = r_w + g4 * 4 + r;
    ef4[r] = efac[row];
    ps4[r] = psr[row];
  }
#pragma unroll
  for (int wi = 0; wi < 3; ++wi) {
    int c = wi * 64 + cq * 16 + l15;
#pragma unroll
    for (int r = 0; r < 4; ++r)
      qpL[r_w + g4 * 4 + r][c] = (f16)(sacc[wi][r] * ef4[r] - dacc[wi][r] * ps4[r]);
  }
  __syncthreads();  // B6

  // ---- PV (A from LDS dots tile, B from prefetched vTT regs) ----
  f32x4 oacc = (f32x4){0.f, 0.f, 0.f, 0.f};
#pragma unroll
  for (int kk = 0; kk < 6; ++kk) {
    f16x8 av = *(const f16x8*)&qpL[r_w + l15][kk * 32 + g4 * 8];
    oacc = MFMA16(av, bvv[kk], oacc);
  }
  {
    int d = cq * 16 + l15;
#pragma unroll
    for (int r = 0; r < 4; ++r) {
      int row = r_w + g4 * 4 + r;
      out[(((size_t)b * T_ + t0g + row) * H_ + h) * E_ + d] =
          oacc[r] + 4.0f * qkv[0][r] * ps4[r];
    }
  }
}

extern "C" void kernel_launch(void* const* d_in, const int* in_sizes, int n_in,
                              void* d_out, int out_size, void* d_ws, size_t ws_size,
                              hipStream_t stream) {
  const float* query = (const float*)d_in[0];
  const float* key   = (const float*)d_in[1];
  const float* value = (const float*)d_in[2];
  const float* proj  = (const float*)d_in[3];
  float* out = (float*)d_out;

  char* ws = (char*)d_ws;
  unsigned* skb = (unsigned*)ws;
  f16* projh    = (f16*)(ws + 256);
  f16* ksh      = (f16*)(ws + 33024);
  float* kd     = (float*)(ws + 6324480);
  f16* k_prime  = (f16*)(ws + 6521088);
  f16* vTT      = (f16*)(ws + 31686912);
  float* kvacc8 = (float*)(ws + 37978368);
  f16* kvT      = (f16*)(ws + 50757888);

  init_ws<<<64, 256, 0, stream>>>(skb, projh, proj);
  prep_k<<<B_ * H_ * 8, 512, 0, stream>>>(key, projh, skb, ksh, kd);
  kpv_kernel<<<B_ * H_ * 8, 512, 0, stream>>>(value, ksh, kd, projh, skb, k_prime, kvacc8, vTT);
  kvred_kernel<<<480, 256, 0, stream>>>(kvacc8, kvT);
  main_fused<<<B_ * H_ * 64, 512, 0, stream>>>(query, ksh, projh, k_prime, kvT, vTT, skb, out);
}